// Round 12
// baseline (358.512 us; speedup 1.0000x reference)
//
#include <hip/hip_runtime.h>

typedef __attribute__((ext_vector_type(8))) short short8;
typedef __attribute__((ext_vector_type(4))) float f32x4;
typedef _Float16 half8v __attribute__((ext_vector_type(8)));

__device__ __forceinline__ unsigned short f2bf(float f) {
    unsigned u = __float_as_uint(f);
    u += 0x7FFFu + ((u >> 16) & 1u);
    return (unsigned short)(u >> 16);
}
__device__ __forceinline__ float bf2f(unsigned short h) {
    return __uint_as_float((unsigned)h << 16);
}

// =====================================================================
// gemm_v7: C[M,Nb] = A[M,K](bf16) @ B[K,Nb](bf16, pre-packed) (+bias)(*rowscale)
template<int MF, int OUTMODE>
__global__ __launch_bounds__(256)
void gemm_v7(const unsigned short* __restrict__ A, const unsigned short* __restrict__ B,
             const float* __restrict__ bias, const float* __restrict__ rowscale,
             void* __restrict__ Cv, const float* __restrict__ fin_num,
             const float* __restrict__ fin_den,
             int M, int Nb, int K, int ldc)
{
    __shared__ alignas(16) unsigned short As[MF * 64 * 32];
    __shared__ alignas(16) unsigned short Bs[4 * 64 * 8];
    const int t = threadIdx.x;
    const int w = t >> 6, l = t & 63;
    const int r16 = l & 15, kg = l >> 4;
    const int row0 = blockIdx.x * (64 * MF);
    const int col0 = blockIdx.y * 64;
    const int bcol = t & 63, bkg = t >> 6;

    f32x4 acc[MF][4] = {};
    const short8 z8 = {0, 0, 0, 0, 0, 0, 0, 0};

    int srow[MF], sch[MF];
    bool va[MF];
    const unsigned short* aptr[MF];
#pragma unroll
    for (int it = 0; it < MF; ++it) {
        int idx = it * 256 + t;
        srow[it] = idx >> 2; sch[it] = idx & 3;
        int gm = row0 + srow[it];
        va[it] = gm < M;
        aptr[it] = A + (size_t)gm * K + sch[it] * 8;
    }
    const unsigned short* bptr = B + (size_t)(bkg * 8) * Nb + col0 + bcol;

    short8 pa[MF];
    unsigned short pbv[8];
#pragma unroll
    for (int it = 0; it < MF; ++it)
        pa[it] = va[it] ? *reinterpret_cast<const short8*>(aptr[it]) : z8;
#pragma unroll
    for (int j = 0; j < 8; ++j) pbv[j] = bptr[(size_t)j * Nb];

    for (int k0 = 0; k0 < K; k0 += 32) {
#pragma unroll
        for (int it = 0; it < MF; ++it)
            *reinterpret_cast<short8*>(&As[srow[it] * 32 + sch[it] * 8]) = pa[it];
        {
            short8 hv;
#pragma unroll
            for (int j = 0; j < 8; ++j) hv[j] = (short)pbv[j];
            *reinterpret_cast<short8*>(&Bs[bkg * 512 + bcol * 8]) = hv;
        }
        __syncthreads();
        if (k0 + 32 < K) {
#pragma unroll
            for (int it = 0; it < MF; ++it)
                pa[it] = va[it] ? *reinterpret_cast<const short8*>(aptr[it] + k0 + 32) : z8;
#pragma unroll
            for (int j = 0; j < 8; ++j) pbv[j] = bptr[(size_t)(k0 + 32 + j) * Nb];
        }
        short8 af[MF];
#pragma unroll
        for (int mi = 0; mi < MF; ++mi)
            af[mi] = *reinterpret_cast<const short8*>(&As[((w * MF + mi) * 16 + r16) * 32 + kg * 8]);
#pragma unroll
        for (int ni = 0; ni < 4; ++ni) {
            short8 bf = *reinterpret_cast<const short8*>(&Bs[kg * 512 + (ni * 16 + r16) * 8]);
#pragma unroll
            for (int mi = 0; mi < MF; ++mi)
                acc[mi][ni] = __builtin_amdgcn_mfma_f32_16x16x32_bf16(af[mi], bf, acc[mi][ni], 0, 0, 0);
        }
        __syncthreads();
    }
#pragma unroll
    for (int mi = 0; mi < MF; ++mi)
#pragma unroll
        for (int ni = 0; ni < 4; ++ni) {
            int col = col0 + ni * 16 + r16;
            float bv = bias ? bias[col] : 0.f;
#pragma unroll
            for (int r = 0; r < 4; ++r) {
                int gm = row0 + (w * MF + mi) * 16 + kg * 4 + r;
                if (gm < M) {
                    float val = acc[mi][ni][r] + bv;
                    if (rowscale) val *= rowscale[gm];
                    size_t idx = (size_t)gm * ldc + col;
                    if (OUTMODE == 0) {
                        ((float*)Cv)[idx] = val;
                    } else if (OUTMODE == 1) {
                        ((unsigned short*)Cv)[idx] = f2bf(val);
                    } else {
                        float d = fin_den[(size_t)gm * 16 + (col >> 5)];
                        float inv = (d > 0.f) ? __fdividef(1.f, d) : 0.f;
                        float o = fmaxf(fin_num[idx] * inv + val, 0.f);
                        ((unsigned short*)Cv)[idx] = f2bf(o);
                    }
                }
            }
        }
}

// =====================================================================
// encoder v5: BARRIER-FREE. One wave per 16-row tile; weights pre-packed in
// MFMA B-fragment layout (1KB contiguous per wave-load); A-frags direct from
// global (line-coalesced); no LDS. Depth-1 register prefetch, static names.
__global__ __launch_bounds__(256)
void enc_f16v5(const float* __restrict__ text, const float* __restrict__ audio, const float* __restrict__ vision,
               const _Float16* __restrict__ Wf16,
               const float* __restrict__ bt, const float* __restrict__ ba, const float* __restrict__ bv,
               float* __restrict__ Cf, unsigned short* __restrict__ Cb, int M)
{
    const int gw = (blockIdx.x * blockDim.x + threadIdx.x) >> 6;   // global wave id
    const int l = threadIdx.x & 63;
    const int tpm = M >> 4;                                        // tiles per modality
    if (gw >= 3 * tpm) return;
    const int z = gw / tpm;
    const int tile = gw - z * tpm;
    const float* A  = (z == 0) ? text : (z == 1) ? audio : vision;
    const _Float16* Wp = Wf16 + ((z == 0) ? 0 : (z == 1) ? 65536 : 98304) + l * 8;
    const float* bb = (z == 0) ? bt : (z == 1) ? ba : bv;
    const int KC = (z == 1) ? 16 : 32;            // K/32

    const float* ap = A + (size_t)(tile * 16 + (l & 15)) * (KC * 32) + (l >> 4) * 8;

    f32x4 acc0 = {}, acc1 = {}, acc2 = {}, acc3 = {};
    float4 na0 = *reinterpret_cast<const float4*>(ap);
    float4 na1 = *reinterpret_cast<const float4*>(ap + 4);
    half8v nb0 = *reinterpret_cast<const half8v*>(Wp);
    half8v nb1 = *reinterpret_cast<const half8v*>(Wp + 512);
    half8v nb2 = *reinterpret_cast<const half8v*>(Wp + 1024);
    half8v nb3 = *reinterpret_cast<const half8v*>(Wp + 1536);

    for (int kc = 0; kc < KC; ++kc) {
        float4 ca0 = na0, ca1 = na1;
        half8v cb0 = nb0, cb1 = nb1, cb2 = nb2, cb3 = nb3;
        if (kc + 1 < KC) {
            const float* apn = ap + (kc + 1) * 32;
            na0 = *reinterpret_cast<const float4*>(apn);
            na1 = *reinterpret_cast<const float4*>(apn + 4);
            const _Float16* wpn = Wp + (size_t)(kc + 1) * 2048;
            nb0 = *reinterpret_cast<const half8v*>(wpn);
            nb1 = *reinterpret_cast<const half8v*>(wpn + 512);
            nb2 = *reinterpret_cast<const half8v*>(wpn + 1024);
            nb3 = *reinterpret_cast<const half8v*>(wpn + 1536);
        }
        half8v af;
        af[0] = (_Float16)ca0.x; af[1] = (_Float16)ca0.y;
        af[2] = (_Float16)ca0.z; af[3] = (_Float16)ca0.w;
        af[4] = (_Float16)ca1.x; af[5] = (_Float16)ca1.y;
        af[6] = (_Float16)ca1.z; af[7] = (_Float16)ca1.w;
        acc0 = __builtin_amdgcn_mfma_f32_16x16x32_f16(af, cb0, acc0, 0, 0, 0);
        acc1 = __builtin_amdgcn_mfma_f32_16x16x32_f16(af, cb1, acc1, 0, 0, 0);
        acc2 = __builtin_amdgcn_mfma_f32_16x16x32_f16(af, cb2, acc2, 0, 0, 0);
        acc3 = __builtin_amdgcn_mfma_f32_16x16x32_f16(af, cb3, acc3, 0, 0, 0);
    }

    const int r16 = l & 15, hi = l >> 4;
#pragma unroll
    for (int cg = 0; cg < 4; ++cg) {
        f32x4 a = (cg == 0) ? acc0 : (cg == 1) ? acc1 : (cg == 2) ? acc2 : acc3;
        int col = cg * 16 + r16;
        float bvv = bb[col];
#pragma unroll
        for (int r = 0; r < 4; ++r) {
            int row = tile * 16 + hi * 4 + r;
            size_t idx = (size_t)row * 192 + z * 64 + col;
            float val = a[r] + bvv;
            Cf[idx] = val;
            Cb[idx] = f2bf(val);
        }
    }
}

// =====================================================================
// one fused weight-pack kernel. Encoder weights now packed into MFMA B-frag
// layout: encW[base + kc*2048 + cg*512 + lane*8 + j] =
//         W[(kc*32 + (lane>>4)*8 + j) * 64 + cg*16 + (lane&15)]
__global__ void pack_all(const float* __restrict__ Wt, const float* __restrict__ Wa, const float* __restrict__ Wv,
                         const float* __restrict__ Wgc,
                         const float* __restrict__ Ws2, const float* __restrict__ Wd2, const float* __restrict__ Wr2,
                         const float* __restrict__ bs2, const float* __restrict__ bd2,
                         const float* __restrict__ Ws0, const float* __restrict__ Wd0,
                         const float* __restrict__ bs0, const float* __restrict__ bd0,
                         const float* __restrict__ Wr0,
                         const float* __restrict__ Ws1, const float* __restrict__ Wd1, const float* __restrict__ Wr1,
                         const float* __restrict__ bs1, const float* __restrict__ bd1,
                         _Float16* __restrict__ encW, unsigned short* __restrict__ Wall, float* __restrict__ ball)
{
    int gid = blockIdx.x * blockDim.x + threadIdx.x;
    if (gid < 163840) {
        const float* Wsrcp;
        int base;
        if (gid < 65536)      { base = 0;     Wsrcp = Wt; }
        else if (gid < 98304) { base = 65536; Wsrcp = Wa; }
        else                  { base = 98304; Wsrcp = Wv; }
        int i = gid - base;
        int kc = i >> 11, r = i & 2047;
        int cg = r >> 9, lane = (r >> 3) & 63, j = r & 7;
        int k = kc * 32 + (lane >> 4) * 8 + j;
        int col = cg * 16 + (lane & 15);
        encW[gid] = (_Float16)Wsrcp[k * 64 + col];
    }
    if (gid < 36864) {
        Wall[gid] = f2bf(Wgc[gid]);
    } else if (gid < 73728) {
        int i = gid - 36864, k = i / 192, c = i - k * 192;
        float v = (c < 64) ? Ws2[k * 64 + c] : (c < 128) ? Wd2[k * 64 + c - 64] : Wr2[k * 64 + c - 128];
        Wall[gid] = f2bf(v);
    } else if (gid < 270336) {
        int i = gid - 73728, k = i >> 10, c = i & 1023;
        float v = (c < 512) ? Ws0[k * 512 + c] : Wd0[k * 512 + c - 512];
        Wall[gid] = f2bf(v);
    } else if (gid < 368640) {
        Wall[gid] = f2bf(Wr0[gid - 270336]);
    } else if (gid < 466944) {
        int i = gid - 368640, k = i / 192, c = i - k * 192;
        float v = (c < 64) ? Ws1[k * 64 + c] : (c < 128) ? Wd1[k * 64 + c - 64] : Wr1[k * 64 + c - 128];
        Wall[gid] = f2bf(v);
    } else if (gid < 468352) {
        int i = gid - 466944;
        float v;
        if (i < 192)       v = (i < 64) ? bs2[i] : (i < 128) ? bd2[i - 64] : 0.f;
        else if (i < 1216) { int j = i - 192; v = (j < 512) ? bs0[j] : bd0[j - 512]; }
        else               { int j = i - 1216; v = (j < 64) ? bs1[j] : (j < 128) ? bd1[j - 64] : 0.f; }
        ball[i] = v;
    }
}

// ---------------- graph preprocessing
__global__ void deg_kernel(const int* __restrict__ src, const int* __restrict__ dst,
                           int* degout, int* degin, int E)
{
    int e = blockIdx.x * blockDim.x + threadIdx.x;
    if (e < E) {
        atomicAdd(&degout[src[e]], 1);
        atomicAdd(&degin[dst[e]], 1);
    }
}

// scan + rs factors fused (degrees are final when this runs)
__global__ __launch_bounds__(1024)
void scan_kernel(const int* __restrict__ degin, const int* __restrict__ degout,
                 int* __restrict__ rowstart, float* __restrict__ rso, float* __restrict__ rsi, int n)
{
    __shared__ int part[1024];
    int t = threadIdx.x;
    int chunk = (n + 1023) / 1024;
    int s = 0;
    for (int i = 0; i < chunk; ++i) {
        int idx = t * chunk + i;
        if (idx < n) s += degin[idx];
    }
    part[t] = s;
    __syncthreads();
    for (int o = 1; o < 1024; o <<= 1) {
        int v = (t >= o) ? part[t - o] : 0;
        __syncthreads();
        part[t] += v;
        __syncthreads();
    }
    int run = (t > 0) ? part[t - 1] : 0;
    for (int i = 0; i < chunk; ++i) {
        int idx = t * chunk + i;
        if (idx < n) {
            rowstart[idx] = run; run += degin[idx];
            rso[idx] = rsqrtf((float)max(degout[idx], 1));
            rsi[idx] = rsqrtf((float)max(degin[idx], 1));
        }
    }
    if (t == 1023) rowstart[n] = part[1023];
}

__global__ void perm_kernel(const int* __restrict__ dst, const int* __restrict__ rowstart,
                            int* cursor, int* __restrict__ perm, int E)
{
    int e = blockIdx.x * blockDim.x + threadIdx.x;
    if (e < E) {
        int v = dst[e];
        int p = atomicAdd(&cursor[v], 1);
        perm[rowstart[v] + p] = e;
    }
}

__global__ void gather_src_kernel(const int* __restrict__ esrc, int* perm, int E)
{
    int i = blockIdx.x * blockDim.x + threadIdx.x;
    if (i < E) perm[i] = esrc[perm[i]];
}

// ---------------- LSTM
__global__ void lstm_pre(const float* __restrict__ x, const float* __restrict__ Wf,
                         const float* __restrict__ Wb,
                         const float* bf1, const float* bf2, const float* bb1, const float* bb2,
                         float* __restrict__ xWf, float* __restrict__ xWb, int n)
{
    int gid = blockIdx.x * blockDim.x + threadIdx.x;
    if (gid >= n * 32) return;
    int nn = gid >> 5, r = gid & 31, d = r >> 4, j = r & 15;
    const float* W = (d ? Wb : Wf) + j * 192;
    const float* xr = x + (size_t)nn * 192;
    float s = 0.f;
#pragma unroll 4
    for (int k = 0; k < 192; k += 4) {
        float4 xv = *reinterpret_cast<const float4*>(xr + k);
        float4 wv = *reinterpret_cast<const float4*>(W + k);
        s += xv.x * wv.x + xv.y * wv.y + xv.z * wv.z + xv.w * wv.w;
    }
    s += d ? (bb1[j] + bb2[j]) : (bf1[j] + bf2[j]);
    int b = nn / 120, tt = nn - b * 120;
    (d ? xWb : xWf)[((size_t)b * 16 + j) * 120 + tt] = s;
}

__device__ __forceinline__ float fsigm(float x) { return __fdividef(1.f, 1.f + __expf(-x)); }
__device__ __forceinline__ float ftanh(float x) { return 1.f - __fdividef(2.f, __expf(2.f * x) + 1.f); }

template<int DIR>
__device__ void lstm_chain(const float* __restrict__ xw, const float* __restrict__ whh,
                           float* __restrict__ newF, int b)
{
    int j = threadIdx.x & 15;
    int k = j & 3;
    float4 w = *reinterpret_cast<const float4*>(whh + j * 4);
    const float* xp = xw + ((size_t)b * 16 + j) * 120;
    float h0 = 0.f, h1 = 0.f, h2 = 0.f, h3 = 0.f, cst = 0.f;
    int tb0 = DIR ? 108 : 0;
    float4 a0 = *reinterpret_cast<const float4*>(xp + tb0);
    float4 a1 = *reinterpret_cast<const float4*>(xp + tb0 + 4);
    float4 a2 = *reinterpret_cast<const float4*>(xp + tb0 + 8);
    for (int ch = 0; ch < 10; ++ch) {
        float4 b0 = a0, b1 = a1, b2 = a2;
        if (ch < 9) {
            int nt = DIR ? (96 - ch * 12) : (12 + ch * 12);
            b0 = *reinterpret_cast<const float4*>(xp + nt);
            b1 = *reinterpret_cast<const float4*>(xp + nt + 4);
            b2 = *reinterpret_cast<const float4*>(xp + nt + 8);
        }
        float zz[12] = {a0.x, a0.y, a0.z, a0.w, a1.x, a1.y, a1.z, a1.w, a2.x, a2.y, a2.z, a2.w};
        int tbase = DIR ? (108 - ch * 12) : (ch * 12);
#pragma unroll
        for (int ii = 0; ii < 12; ++ii) {
            int idx = DIR ? (11 - ii) : ii;
            float z = zz[idx] + ((w.x * h0 + w.y * h1) + (w.z * h2 + w.w * h3));
            float zi = __shfl(z, k, 16);
            float zf = __shfl(z, k + 4, 16);
            float zg = __shfl(z, k + 8, 16);
            float zo = __shfl(z, k + 12, 16);
            float ig = fsigm(zi), fg = fsigm(zf), gg = ftanh(zg), og = fsigm(zo);
            cst = fg * cst + ig * gg;
            float hn = og * ftanh(cst);
            h0 = __shfl(hn, 0, 16); h1 = __shfl(hn, 1, 16);
            h2 = __shfl(hn, 2, 16); h3 = __shfl(hn, 3, 16);
            if (j < 4) newF[((size_t)b * 120 + tbase + idx) * 8 + DIR * 4 + j] = hn;
        }
        a0 = b0; a1 = b1; a2 = b2;
    }
}

__global__ __launch_bounds__(64)
void lstm_seq2(const float* __restrict__ xWf, const float* __restrict__ xWb,
               const float* __restrict__ Whhf, const float* __restrict__ Whhb,
               float* __restrict__ newF, int B)
{
    int sub = threadIdx.x >> 4;
    int chain = blockIdx.x * 4 + sub;
    if (chain >= 2 * B) return;
    int d = chain / B;
    int b = chain - d * B;
    if (d == 0) lstm_chain<0>(xWf, Whhf, newF, b);
    else        lstm_chain<1>(xWb, Whhb, newF, b);
}

// ---------------- GraphConv combine + L1 norm: 2-edge software pipeline
__global__ __launch_bounds__(256)
void gc_combine5(const float* __restrict__ stackFT, const unsigned short* __restrict__ hw,
                 const int* __restrict__ rowstart, const int* __restrict__ csrc,
                 const float* __restrict__ rs_in,
                 const float* __restrict__ b_gc, unsigned short* __restrict__ hB, int n)
{
    int v = blockIdx.x * 4 + (threadIdx.x >> 6);
    int l = threadIdx.x & 63;
    if (v >= n) return;
    int s0 = rowstart[v], s1 = rowstart[v + 1];
    float sum0 = 0.f, sum1 = 0.f, sum2 = 0.f;

    unsigned short a0 = 0, a1 = 0, a2 = 0, b0 = 0, b1 = 0, b2 = 0;
    auto LD = [&](int i, unsigned short& x0, unsigned short& x1, unsigned short& x2) {
        const unsigned short* hr = hw + (size_t)csrc[i] * 192 + l;
        x0 = hr[0]; x1 = hr[64]; x2 = hr[128];
    };
    int i = s0;
    if (i < s1) LD(i, a0, a1, a2);
    if (i + 1 < s1) LD(i + 1, b0, b1, b2);
    for (; i + 2 < s1; i += 2) {
        unsigned short n0, n1, n2, m0 = 0, m1 = 0, m2 = 0;
        LD(i + 2, n0, n1, n2);
        if (i + 3 < s1) LD(i + 3, m0, m1, m2);
        sum0 += bf2f(a0) + bf2f(b0);
        sum1 += bf2f(a1) + bf2f(b1);
        sum2 += bf2f(a2) + bf2f(b2);
        a0 = n0; a1 = n1; a2 = n2; b0 = m0; b1 = m1; b2 = m2;
    }
    if (i < s1) { sum0 += bf2f(a0); sum1 += bf2f(a1); sum2 += bf2f(a2); }
    if (i + 1 < s1) { sum0 += bf2f(b0); sum1 += bf2f(b1); sum2 += bf2f(b2); }

    float ri = rs_in[v];
    const float* sf = stackFT + (size_t)v * 192 + l;
    float v0 = 0.5f * (sf[0]   + sum0 * ri + b_gc[l]);
    float v1 = 0.5f * (sf[64]  + sum1 * ri + b_gc[l + 64]);
    float v2 = 0.5f * (sf[128] + sum2 * ri + b_gc[l + 128]);
    float r = fabsf(v0) + fabsf(v1) + fabsf(v2);
#pragma unroll
    for (int o = 32; o; o >>= 1) r += __shfl_xor(r, o);
    float inv = __fdividef(1.f, fmaxf(r, 1e-12f));
    unsigned short* hp = hB + (size_t)v * 192 + l;
    hp[0]   = f2bf(v0 * inv);
    hp[64]  = f2bf(v1 * inv);
    hp[128] = f2bf(v2 * inv);
}

// ---------------- GATv2 F=4 (HF=64): 16 lanes/node, 2-edge pipeline, fused epilogue
__global__ __launch_bounds__(256)
void gat_edge4c(const unsigned short* __restrict__ base, // [n,192] bf16 fs|fd|res
                const float* __restrict__ attn,
                const int* __restrict__ rowstart, const int* __restrict__ csrc,
                float* __restrict__ outp, int n)
{
    int v = blockIdx.x * 16 + (threadIdx.x >> 4);
    int l = threadIdx.x & 15;
    if (v >= n) return;
    float4 at = *reinterpret_cast<const float4*>(attn + l * 4);
    ushort4 fdu = *reinterpret_cast<const ushort4*>(base + (size_t)v * 192 + 64 + l * 4);
    float fd0 = bf2f(fdu.x), fd1 = bf2f(fdu.y), fd2 = bf2f(fdu.z), fd3 = bf2f(fdu.w);
    float ac0 = 0.f, ac1 = 0.f, ac2 = 0.f, ac3 = 0.f, dn = 0.f;
    int s0 = rowstart[v], s1 = rowstart[v + 1];

    auto LD = [&](int i) -> ushort4 {
        return *reinterpret_cast<const ushort4*>(base + (size_t)csrc[i] * 192 + l * 4);
    };
    auto ACC = [&](ushort4 su) {
        float s0f = bf2f(su.x), s1f = bf2f(su.y), s2f = bf2f(su.z), s3f = bf2f(su.w);
        float e0 = s0f + fd0; e0 = fmaxf(e0, 0.2f * e0);
        float e1 = s1f + fd1; e1 = fmaxf(e1, 0.2f * e1);
        float e2 = s2f + fd2; e2 = fmaxf(e2, 0.2f * e2);
        float e3 = s3f + fd3; e3 = fmaxf(e3, 0.2f * e3);
        float p = e0 * at.x + e1 * at.y + e2 * at.z + e3 * at.w;
        float ex = __expf(p);
        ac0 += ex * s0f; ac1 += ex * s1f; ac2 += ex * s2f; ac3 += ex * s3f;
        dn += ex;
    };
    const ushort4 zu = make_ushort4(0, 0, 0, 0);
    ushort4 c0 = zu, c1 = zu;
    int i = s0;
    if (i < s1) c0 = LD(i);
    if (i + 1 < s1) c1 = LD(i + 1);
    for (; i + 2 < s1; i += 2) {
        ushort4 n0 = LD(i + 2);
        ushort4 n1 = (i + 3 < s1) ? LD(i + 3) : zu;
        ACC(c0); ACC(c1);
        c0 = n0; c1 = n1;
    }
    if (i < s1) ACC(c0);
    if (i + 1 < s1) ACC(c1);

    ushort4 ru = *reinterpret_cast<const ushort4*>(base + (size_t)v * 192 + 128 + l * 4);
    float inv = (dn > 0.f) ? __fdividef(1.f, dn) : 0.f;
    float4 o;
    o.x = fmaxf(ac0 * inv + bf2f(ru.x), 0.f);
    o.y = fmaxf(ac1 * inv + bf2f(ru.y), 0.f);
    o.z = fmaxf(ac2 * inv + bf2f(ru.z), 0.f);
    o.w = fmaxf(ac3 * inv + bf2f(ru.w), 0.f);
    *reinterpret_cast<float4*>(outp + (size_t)v * 64 + l * 4) = o;
}

// ---------------- GATv2 F=32 (HF=512): one wave per node, 8 elems/lane, 2-edge pipeline
__global__ __launch_bounds__(256)
void gat_edge32b(const unsigned short* __restrict__ base,   // [n,1024] bf16 fs|fd
                 const float* __restrict__ attn,
                 const int* __restrict__ rowstart, const int* __restrict__ csrc,
                 float* __restrict__ num, float* __restrict__ den, int n)
{
    int v = blockIdx.x * 4 + (threadIdx.x >> 6);
    int l = threadIdx.x & 63;
    if (v >= n) return;
    float at[8];
    {
        float4 aA = *reinterpret_cast<const float4*>(attn + l * 8);
        float4 aB = *reinterpret_cast<const float4*>(attn + l * 8 + 4);
        at[0] = aA.x; at[1] = aA.y; at[2] = aA.z; at[3] = aA.w;
        at[4] = aB.x; at[5] = aB.y; at[6] = aB.z; at[7] = aB.w;
    }
    float fd[8];
    {
        short8 fdu = *reinterpret_cast<const short8*>(base + (size_t)v * 1024 + 512 + l * 8);
#pragma unroll
        for (int j = 0; j < 8; ++j) fd[j] = bf2f((unsigned short)fdu[j]);
    }
    float acc[8] = {};
    float dn = 0.f;
    int s0 = rowstart[v], s1 = rowstart[v + 1];

    auto LD = [&](int i) -> short8 {
        return *reinterpret_cast<const short8*>(base + (size_t)csrc[i] * 1024 + l * 8);
    };
    auto ACC = [&](short8 su) {
        float sf[8];
        float p = 0.f;
#pragma unroll
        for (int j = 0; j < 8; ++j) {
            sf[j] = bf2f((unsigned short)su[j]);
            float e = sf[j] + fd[j];
            e = fmaxf(e, 0.2f * e);
            p += e * at[j];
        }
        p += __shfl_xor(p, 1, 4);
        p += __shfl_xor(p, 2, 4);
        float ex = __expf(p);
#pragma unroll
        for (int j = 0; j < 8; ++j) acc[j] += ex * sf[j];
        dn += ex;
    };
    const short8 z8 = {0, 0, 0, 0, 0, 0, 0, 0};
    short8 c0 = z8, c1 = z8;
    int i = s0;
    if (i < s1) c0 = LD(i);
    if (i + 1 < s1) c1 = LD(i + 1);
    for (; i + 2 < s1; i += 2) {
        short8 n0 = LD(i + 2);
        short8 n1 = (i + 3 < s1) ? LD(i + 3) : z8;
        ACC(c0); ACC(c1);
        c0 = n0; c1 = n1;
    }
    if (i < s1) ACC(c0);
    if (i + 1 < s1) ACC(c1);

    float* np = num + (size_t)v * 512 + l * 8;
    *reinterpret_cast<float4*>(np)     = make_float4(acc[0], acc[1], acc[2], acc[3]);
    *reinterpret_cast<float4*>(np + 4) = make_float4(acc[4], acc[5], acc[6], acc[7]);
    if ((l & 3) == 0) den[(size_t)v * 16 + (l >> 2)] = dn;
}

// ---------------- final classifier
__global__ void final_lin(const float* __restrict__ h1, const float* __restrict__ newF,
                          const float* __restrict__ h3, const float* __restrict__ W,
                          const float* __restrict__ bias, float* __restrict__ out, int n)
{
    int gid = blockIdx.x * blockDim.x + threadIdx.x;
    if (gid >= n * 6) return;
    int v = gid / 6, o = gid - v * 6;
    float s = bias[o];
    const float* a = h1 + (size_t)v * 64;
#pragma unroll 8
    for (int r = 0; r < 64; ++r) s += a[r] * W[r * 6 + o];
    const float* b = newF + (size_t)v * 8;
#pragma unroll
    for (int r = 0; r < 8; ++r) s += b[r] * W[(64 + r) * 6 + o];
    const float* c = h3 + (size_t)v * 64;
#pragma unroll 8
    for (int r = 0; r < 64; ++r) s += c[r] * W[(72 + r) * 6 + o];
    out[gid] = s;
}

// ----------------------------------------------------------------------------
extern "C" void kernel_launch(void* const* d_in, const int* in_sizes, int n_in,
                              void* d_out, int out_size, void* d_ws, size_t ws_size,
                              hipStream_t stream)
{
    const float* text   = (const float*)d_in[0];
    const float* audio  = (const float*)d_in[1];
    const float* vision = (const float*)d_in[2];
    const int*   esrc   = (const int*)d_in[3];
    const int*   edst   = (const int*)d_in[4];
    const float* W_audio = (const float*)d_in[5];  const float* b_audio = (const float*)d_in[6];
    const float* W_vision= (const float*)d_in[7];  const float* b_vision= (const float*)d_in[8];
    const float* W_text  = (const float*)d_in[9];  const float* b_text  = (const float*)d_in[10];
    const float* Wih_f = (const float*)d_in[11]; const float* Whh_f = (const float*)d_in[12];
    const float* bih_f = (const float*)d_in[13]; const float* bhh_f = (const float*)d_in[14];
    const float* Wih_b = (const float*)d_in[15]; const float* Whh_b = (const float*)d_in[16];
    const float* bih_b = (const float*)d_in[17]; const float* bhh_b = (const float*)d_in[18];
    const float* W_gc  = (const float*)d_in[19]; const float* b_gc  = (const float*)d_in[20];
    const float* Wsrc2 = (const float*)d_in[21]; const float* bsrc2 = (const float*)d_in[22];
    const float* Wdst2 = (const float*)d_in[23]; const float* bdst2 = (const float*)d_in[24];
    const float* attn2 = (const float*)d_in[25]; const float* Wres2 = (const float*)d_in[26];
    const float* Wsrc0 = (const float*)d_in[27]; const float* bsrc0 = (const float*)d_in[28];
    const float* Wdst0 = (const float*)d_in[29]; const float* bdst0 = (const float*)d_in[30];
    const float* attn0 = (const float*)d_in[31]; const float* Wres0 = (const float*)d_in[32];
    const float* Wsrc1 = (const float*)d_in[33]; const float* bsrc1 = (const float*)d_in[34];
    const float* Wdst1 = (const float*)d_in[35]; const float* bdst1 = (const float*)d_in[36];
    const float* attn1 = (const float*)d_in[37]; const float* Wres1 = (const float*)d_in[38];
    const float* W_lin = (const float*)d_in[39]; const float* b_lin = (const float*)d_in[40];
    float* out = (float*)d_out;

    const int n = in_sizes[0] / 1024;   // 12000
    const int E = in_sizes[3];          // 192000
    const int B = n / 120;              // 100

    // ---- workspace carve (256B aligned)
    char* p = (char*)d_ws;
    auto alloc_f = [&](size_t cnt) { float* r = (float*)p; p += ((cnt * 4 + 255) / 256) * 256; return r; };
    auto alloc_h = [&](size_t cnt) { unsigned short* r = (unsigned short*)p; p += ((cnt * 2 + 255) / 256) * 256; return r; };
    auto alloc_i = [&](size_t cnt) { int* r = (int*)p; p += ((cnt * 4 + 255) / 256) * 256; return r; };
    float*          stackFT = alloc_f((size_t)n * 192);
    unsigned short* stackBF = alloc_h((size_t)n * 192);
    unsigned short* hbufBF  = alloc_h((size_t)n * 192);
    unsigned short* encW    = alloc_h(163840);
    float* xWf     = alloc_f((size_t)n * 16);
    float* xWb     = alloc_f((size_t)n * 16);
    float* newF    = alloc_f((size_t)n * 8);
    float* big0    = alloc_f((size_t)n * 512);
    float* big1    = alloc_f((size_t)n * 512);
    float* big2    = alloc_f((size_t)n * 512);
    float* den     = alloc_f((size_t)n * 16);
    float* h3      = alloc_f((size_t)n * 64);
    float* h1s     = alloc_f((size_t)n * 64);   // hosts packed weights until gat1 edge writes it
    float* rs_out  = alloc_f(n);
    float* rs_in   = alloc_f(n);
    int* zero_base = alloc_i((size_t)3 * n);
    int* degout = zero_base;
    int* degin  = zero_base + n;
    int* cursor = zero_base + 2 * n;
    int* rowstart = alloc_i((size_t)n + 1);
    int* perm     = alloc_i((size_t)E);
    if ((size_t)(p - (char*)d_ws) > ws_size) return;

    // packed weights live in h1s (dead until gat1 edge): 466944 shorts + 1408 floats
    unsigned short* Wall = (unsigned short*)h1s;
    float* ball = h1s + 240000;
    const unsigned short* Wp_gc = Wall;
    const unsigned short* Wp_g2 = Wall + 36864;
    const unsigned short* Wp_g0 = Wall + 73728;
    const unsigned short* Wp_r0 = Wall + 270336;
    const unsigned short* Wp_g1 = Wall + 368640;
    const float* bp_g2 = ball;
    const float* bp_g0 = ball + 192;
    const float* bp_g1 = ball + 1216;

    // ---- graph preprocessing + one fused weight-pack
    hipMemsetAsync(zero_base, 0, (size_t)3 * n * 4, stream);
    pack_all<<<(468352 + 255) / 256, 256, 0, stream>>>(
        W_text, W_audio, W_vision, W_gc,
        Wsrc2, Wdst2, Wres2, bsrc2, bdst2,
        Wsrc0, Wdst0, bsrc0, bdst0, Wres0,
        Wsrc1, Wdst1, Wres1, bsrc1, bdst1,
        (_Float16*)encW, Wall, ball);
    deg_kernel<<<(E + 255) / 256, 256, 0, stream>>>(esrc, edst, degout, degin, E);
    scan_kernel<<<1, 1024, 0, stream>>>(degin, degout, rowstart, rs_out, rs_in, n);
    perm_kernel<<<(E + 255) / 256, 256, 0, stream>>>(edst, rowstart, cursor, perm, E);
    gather_src_kernel<<<(E + 255) / 256, 256, 0, stream>>>(esrc, perm, E);
    const int* csrc = perm;

    auto gemm = [&](auto mf_tag, auto om_tag, const unsigned short* A, const unsigned short* Bm,
                    const float* bias, const float* rsc, void* Cp,
                    const float* fnum, const float* fden, int M, int Nb, int K, int ldc) {
        constexpr int MF = decltype(mf_tag)::value;
        constexpr int OM = decltype(om_tag)::value;
        dim3 grid((M + 64 * MF - 1) / (64 * MF), Nb / 64);
        gemm_v7<MF, OM><<<grid, 256, 0, stream>>>(A, Bm, bias, rsc, Cp, fnum, fden, M, Nb, K, ldc);
    };
    using I1 = std::integral_constant<int, 1>;
    using I2 = std::integral_constant<int, 2>;
    using O1 = std::integral_constant<int, 1>;
    using O2 = std::integral_constant<int, 2>;

    // ---- modality encoders (barrier-free f16 MFMA, frag-packed weights)
    {
        int waves = 3 * (n >> 4);
        enc_f16v5<<<(waves * 64 + 255) / 256, 256, 0, stream>>>(
            text, audio, vision, (const _Float16*)encW,
            b_text, b_audio, b_vision, stackFT, stackBF, n);
    }

    // ---- BiLSTM
    lstm_pre<<<(n * 32 + 255) / 256, 256, 0, stream>>>(stackFT, Wih_f, Wih_b,
                                                       bih_f, bhh_f, bih_b, bhh_b, xWf, xWb, n);
    lstm_seq2<<<(2 * B + 3) / 4, 64, 0, stream>>>(xWf, xWb, Whh_f, Whh_b, newF, B);

    // ---- GraphConv imputation + L1 norm -> hbufBF (bf16)
    gemm(I1{}, O1{}, stackBF, Wp_gc, nullptr, rs_out, big0, nullptr, nullptr, n, 192, 192, 192);
    gc_combine5<<<(n + 3) / 4, 256, 0, stream>>>(stackFT, (const unsigned short*)big0,
                                                 rowstart, csrc, rs_in, b_gc, hbufBF, n);

    // ---- gat2: packed src|dst|res GEMM -> big0 bf16 [n,192], fused edge -> h3
    gemm(I1{}, O1{}, hbufBF, Wp_g2, bp_g2, nullptr, big0, nullptr, nullptr, n, 192, 192, 192);
    gat_edge4c<<<(n + 15) / 16, 256, 0, stream>>>((const unsigned short*)big0, attn2, rowstart, csrc, h3, n);

    // ---- gat0: packed src|dst GEMM -> big0 bf16 [n,1024]; edge -> big2/den;
    //            res GEMM with fused finalize -> big1 bf16 [n,512]
    gemm(I2{}, O1{}, hbufBF, Wp_g0, bp_g0, nullptr, big0, nullptr, nullptr, n, 1024, 192, 1024);
    gat_edge32b<<<(n + 3) / 4, 256, 0, stream>>>((const unsigned short*)big0, attn0, rowstart, csrc, big2, den, n);
    gemm(I1{}, O2{}, hbufBF, Wp_r0, nullptr, nullptr, big1, big2, den, n, 512, 192, 512);

    // ---- gat1: packed src|dst|res GEMM (A = big1 bf16 [n,512]) -> big0 bf16 [n,192], fused edge -> h1s
    gemm(I1{}, O1{}, (const unsigned short*)big1, Wp_g1, bp_g1, nullptr, big0, nullptr, nullptr, n, 192, 512, 192);
    gat_edge4c<<<(n + 15) / 16, 256, 0, stream>>>((const unsigned short*)big0, attn1, rowstart, csrc, h1s, n);

    // ---- final classifier
    final_lin<<<(n * 6 + 255) / 256, 256, 0, stream>>>(h1s, newF, h3, W_lin, b_lin, out, n);
}

// Round 13
// 357.913 us; speedup vs baseline: 1.0017x; 1.0017x over previous
//
#include <hip/hip_runtime.h>

typedef __attribute__((ext_vector_type(8))) short short8;
typedef __attribute__((ext_vector_type(4))) float f32x4;
typedef _Float16 half8v __attribute__((ext_vector_type(8)));

__device__ __forceinline__ unsigned short f2bf(float f) {
    unsigned u = __float_as_uint(f);
    u += 0x7FFFu + ((u >> 16) & 1u);
    return (unsigned short)(u >> 16);
}
__device__ __forceinline__ float bf2f(unsigned short h) {
    return __uint_as_float((unsigned)h << 16);
}

// =====================================================================
// gemm_v7: C[M,Nb] = A[M,K](bf16) @ B[K,Nb](bf16, pre-packed) (+bias)(*rowscale)
template<int MF, int OUTMODE>
__global__ __launch_bounds__(256)
void gemm_v7(const unsigned short* __restrict__ A, const unsigned short* __restrict__ B,
             const float* __restrict__ bias, const float* __restrict__ rowscale,
             void* __restrict__ Cv, const float* __restrict__ fin_num,
             const float* __restrict__ fin_den,
             int M, int Nb, int K, int ldc)
{
    __shared__ alignas(16) unsigned short As[MF * 64 * 32];
    __shared__ alignas(16) unsigned short Bs[4 * 64 * 8];
    const int t = threadIdx.x;
    const int w = t >> 6, l = t & 63;
    const int r16 = l & 15, kg = l >> 4;
    const int row0 = blockIdx.x * (64 * MF);
    const int col0 = blockIdx.y * 64;
    const int bcol = t & 63, bkg = t >> 6;

    f32x4 acc[MF][4] = {};
    const short8 z8 = {0, 0, 0, 0, 0, 0, 0, 0};

    int srow[MF], sch[MF];
    bool va[MF];
    const unsigned short* aptr[MF];
#pragma unroll
    for (int it = 0; it < MF; ++it) {
        int idx = it * 256 + t;
        srow[it] = idx >> 2; sch[it] = idx & 3;
        int gm = row0 + srow[it];
        va[it] = gm < M;
        aptr[it] = A + (size_t)gm * K + sch[it] * 8;
    }
    const unsigned short* bptr = B + (size_t)(bkg * 8) * Nb + col0 + bcol;

    short8 pa[MF];
    unsigned short pbv[8];
#pragma unroll
    for (int it = 0; it < MF; ++it)
        pa[it] = va[it] ? *reinterpret_cast<const short8*>(aptr[it]) : z8;
#pragma unroll
    for (int j = 0; j < 8; ++j) pbv[j] = bptr[(size_t)j * Nb];

    for (int k0 = 0; k0 < K; k0 += 32) {
#pragma unroll
        for (int it = 0; it < MF; ++it)
            *reinterpret_cast<short8*>(&As[srow[it] * 32 + sch[it] * 8]) = pa[it];
        {
            short8 hv;
#pragma unroll
            for (int j = 0; j < 8; ++j) hv[j] = (short)pbv[j];
            *reinterpret_cast<short8*>(&Bs[bkg * 512 + bcol * 8]) = hv;
        }
        __syncthreads();
        if (k0 + 32 < K) {
#pragma unroll
            for (int it = 0; it < MF; ++it)
                pa[it] = va[it] ? *reinterpret_cast<const short8*>(aptr[it] + k0 + 32) : z8;
#pragma unroll
            for (int j = 0; j < 8; ++j) pbv[j] = bptr[(size_t)(k0 + 32 + j) * Nb];
        }
        short8 af[MF];
#pragma unroll
        for (int mi = 0; mi < MF; ++mi)
            af[mi] = *reinterpret_cast<const short8*>(&As[((w * MF + mi) * 16 + r16) * 32 + kg * 8]);
#pragma unroll
        for (int ni = 0; ni < 4; ++ni) {
            short8 bf = *reinterpret_cast<const short8*>(&Bs[kg * 512 + (ni * 16 + r16) * 8]);
#pragma unroll
            for (int mi = 0; mi < MF; ++mi)
                acc[mi][ni] = __builtin_amdgcn_mfma_f32_16x16x32_bf16(af[mi], bf, acc[mi][ni], 0, 0, 0);
        }
        __syncthreads();
    }
#pragma unroll
    for (int mi = 0; mi < MF; ++mi)
#pragma unroll
        for (int ni = 0; ni < 4; ++ni) {
            int col = col0 + ni * 16 + r16;
            float bv = bias ? bias[col] : 0.f;
#pragma unroll
            for (int r = 0; r < 4; ++r) {
                int gm = row0 + (w * MF + mi) * 16 + kg * 4 + r;
                if (gm < M) {
                    float val = acc[mi][ni][r] + bv;
                    if (rowscale) val *= rowscale[gm];
                    size_t idx = (size_t)gm * ldc + col;
                    if (OUTMODE == 0) {
                        ((float*)Cv)[idx] = val;
                    } else if (OUTMODE == 1) {
                        ((unsigned short*)Cv)[idx] = f2bf(val);
                    } else {
                        float d = fin_den[(size_t)gm * 16 + (col >> 5)];
                        float inv = (d > 0.f) ? __fdividef(1.f, d) : 0.f;
                        float o = fmaxf(fin_num[idx] * inv + val, 0.f);
                        ((unsigned short*)Cv)[idx] = f2bf(o);
                    }
                }
            }
        }
}

// =====================================================================
// encoder v6: barrier-free f16 MFMA (frag-packed weights, direct A), with
// LDS-TRANSPOSED EPILOGUE: tile staged in LDS [16][68], written row-wise
// (256B f32 + 128B bf16 contiguous per wave-store). No __syncthreads.
__global__ __launch_bounds__(256)
void enc_f16v6(const float* __restrict__ text, const float* __restrict__ audio, const float* __restrict__ vision,
               const _Float16* __restrict__ Wf16,
               const float* __restrict__ bt, const float* __restrict__ ba, const float* __restrict__ bv,
               float* __restrict__ Cf, unsigned short* __restrict__ Cb, int M)
{
    __shared__ float tbuf[4][16][68];
    const int gw = (blockIdx.x * blockDim.x + threadIdx.x) >> 6;   // global wave id
    const int wib = threadIdx.x >> 6;                              // wave in block
    const int l = threadIdx.x & 63;
    const int tpm = M >> 4;                                        // tiles per modality
    if (gw >= 3 * tpm) return;
    const int z = gw / tpm;
    const int tidx = gw - z * tpm;
    const float* A  = (z == 0) ? text : (z == 1) ? audio : vision;
    const _Float16* Wp = Wf16 + ((z == 0) ? 0 : (z == 1) ? 65536 : 98304) + l * 8;
    const float* bb = (z == 0) ? bt : (z == 1) ? ba : bv;
    const int KC = (z == 1) ? 16 : 32;            // K/32

    const float* ap = A + (size_t)(tidx * 16 + (l & 15)) * (KC * 32) + (l >> 4) * 8;

    f32x4 acc0 = {}, acc1 = {}, acc2 = {}, acc3 = {};
    float4 na0 = *reinterpret_cast<const float4*>(ap);
    float4 na1 = *reinterpret_cast<const float4*>(ap + 4);
    half8v nb0 = *reinterpret_cast<const half8v*>(Wp);
    half8v nb1 = *reinterpret_cast<const half8v*>(Wp + 512);
    half8v nb2 = *reinterpret_cast<const half8v*>(Wp + 1024);
    half8v nb3 = *reinterpret_cast<const half8v*>(Wp + 1536);

    for (int kc = 0; kc < KC; ++kc) {
        float4 ca0 = na0, ca1 = na1;
        half8v cb0 = nb0, cb1 = nb1, cb2 = nb2, cb3 = nb3;
        if (kc + 1 < KC) {
            const float* apn = ap + (kc + 1) * 32;
            na0 = *reinterpret_cast<const float4*>(apn);
            na1 = *reinterpret_cast<const float4*>(apn + 4);
            const _Float16* wpn = Wp + (size_t)(kc + 1) * 2048;
            nb0 = *reinterpret_cast<const half8v*>(wpn);
            nb1 = *reinterpret_cast<const half8v*>(wpn + 512);
            nb2 = *reinterpret_cast<const half8v*>(wpn + 1024);
            nb3 = *reinterpret_cast<const half8v*>(wpn + 1536);
        }
        half8v af;
        af[0] = (_Float16)ca0.x; af[1] = (_Float16)ca0.y;
        af[2] = (_Float16)ca0.z; af[3] = (_Float16)ca0.w;
        af[4] = (_Float16)ca1.x; af[5] = (_Float16)ca1.y;
        af[6] = (_Float16)ca1.z; af[7] = (_Float16)ca1.w;
        acc0 = __builtin_amdgcn_mfma_f32_16x16x32_f16(af, cb0, acc0, 0, 0, 0);
        acc1 = __builtin_amdgcn_mfma_f32_16x16x32_f16(af, cb1, acc1, 0, 0, 0);
        acc2 = __builtin_amdgcn_mfma_f32_16x16x32_f16(af, cb2, acc2, 0, 0, 0);
        acc3 = __builtin_amdgcn_mfma_f32_16x16x32_f16(af, cb3, acc3, 0, 0, 0);
    }

    const int r16 = l & 15, hi = l >> 4;
    float* tl = &tbuf[wib][0][0];
    // stage (2-way bank alias only, free); no barrier — single-wave tile
#pragma unroll
    for (int cg = 0; cg < 4; ++cg) {
        f32x4 a = (cg == 0) ? acc0 : (cg == 1) ? acc1 : (cg == 2) ? acc2 : acc3;
        int col = cg * 16 + r16;
        float bvv = bb[col];
#pragma unroll
        for (int r = 0; r < 4; ++r)
            tl[(hi * 4 + r) * 68 + col] = a[r] + bvv;
    }
    // row-wise coalesced writes: 256B f32 + 128B bf16 per wave-store
#pragma unroll
    for (int r = 0; r < 16; ++r) {
        float val = tl[r * 68 + l];
        size_t idx = (size_t)(tidx * 16 + r) * 192 + z * 64 + l;
        Cf[idx] = val;
        Cb[idx] = f2bf(val);
    }
}

// =====================================================================
// one fused weight-pack kernel. Encoder weights packed into MFMA B-frag layout.
__global__ void pack_all(const float* __restrict__ Wt, const float* __restrict__ Wa, const float* __restrict__ Wv,
                         const float* __restrict__ Wgc,
                         const float* __restrict__ Ws2, const float* __restrict__ Wd2, const float* __restrict__ Wr2,
                         const float* __restrict__ bs2, const float* __restrict__ bd2,
                         const float* __restrict__ Ws0, const float* __restrict__ Wd0,
                         const float* __restrict__ bs0, const float* __restrict__ bd0,
                         const float* __restrict__ Wr0,
                         const float* __restrict__ Ws1, const float* __restrict__ Wd1, const float* __restrict__ Wr1,
                         const float* __restrict__ bs1, const float* __restrict__ bd1,
                         _Float16* __restrict__ encW, unsigned short* __restrict__ Wall, float* __restrict__ ball)
{
    int gid = blockIdx.x * blockDim.x + threadIdx.x;
    if (gid < 163840) {
        const float* Wsrcp;
        int base;
        if (gid < 65536)      { base = 0;     Wsrcp = Wt; }
        else if (gid < 98304) { base = 65536; Wsrcp = Wa; }
        else                  { base = 98304; Wsrcp = Wv; }
        int i = gid - base;
        int kc = i >> 11, r = i & 2047;
        int cg = r >> 9, lane = (r >> 3) & 63, j = r & 7;
        int k = kc * 32 + (lane >> 4) * 8 + j;
        int col = cg * 16 + (lane & 15);
        encW[gid] = (_Float16)Wsrcp[k * 64 + col];
    }
    if (gid < 36864) {
        Wall[gid] = f2bf(Wgc[gid]);
    } else if (gid < 73728) {
        int i = gid - 36864, k = i / 192, c = i - k * 192;
        float v = (c < 64) ? Ws2[k * 64 + c] : (c < 128) ? Wd2[k * 64 + c - 64] : Wr2[k * 64 + c - 128];
        Wall[gid] = f2bf(v);
    } else if (gid < 270336) {
        int i = gid - 73728, k = i >> 10, c = i & 1023;
        float v = (c < 512) ? Ws0[k * 512 + c] : Wd0[k * 512 + c - 512];
        Wall[gid] = f2bf(v);
    } else if (gid < 368640) {
        Wall[gid] = f2bf(Wr0[gid - 270336]);
    } else if (gid < 466944) {
        int i = gid - 368640, k = i / 192, c = i - k * 192;
        float v = (c < 64) ? Ws1[k * 64 + c] : (c < 128) ? Wd1[k * 64 + c - 64] : Wr1[k * 64 + c - 128];
        Wall[gid] = f2bf(v);
    } else if (gid < 468352) {
        int i = gid - 466944;
        float v;
        if (i < 192)       v = (i < 64) ? bs2[i] : (i < 128) ? bd2[i - 64] : 0.f;
        else if (i < 1216) { int j = i - 192; v = (j < 512) ? bs0[j] : bd0[j - 512]; }
        else               { int j = i - 1216; v = (j < 64) ? bs1[j] : (j < 128) ? bd1[j - 64] : 0.f; }
        ball[i] = v;
    }
}

// ---------------- graph preprocessing
__global__ void deg_kernel(const int* __restrict__ src, const int* __restrict__ dst,
                           int* degout, int* degin, int E)
{
    int e = blockIdx.x * blockDim.x + threadIdx.x;
    if (e < E) {
        atomicAdd(&degout[src[e]], 1);
        atomicAdd(&degin[dst[e]], 1);
    }
}

// scan + rs factors fused (degrees are final when this runs)
__global__ __launch_bounds__(1024)
void scan_kernel(const int* __restrict__ degin, const int* __restrict__ degout,
                 int* __restrict__ rowstart, float* __restrict__ rso, float* __restrict__ rsi, int n)
{
    __shared__ int part[1024];
    int t = threadIdx.x;
    int chunk = (n + 1023) / 1024;
    int s = 0;
    for (int i = 0; i < chunk; ++i) {
        int idx = t * chunk + i;
        if (idx < n) s += degin[idx];
    }
    part[t] = s;
    __syncthreads();
    for (int o = 1; o < 1024; o <<= 1) {
        int v = (t >= o) ? part[t - o] : 0;
        __syncthreads();
        part[t] += v;
        __syncthreads();
    }
    int run = (t > 0) ? part[t - 1] : 0;
    for (int i = 0; i < chunk; ++i) {
        int idx = t * chunk + i;
        if (idx < n) {
            rowstart[idx] = run; run += degin[idx];
            rso[idx] = rsqrtf((float)max(degout[idx], 1));
            rsi[idx] = rsqrtf((float)max(degin[idx], 1));
        }
    }
    if (t == 1023) rowstart[n] = part[1023];
}

__global__ void perm_kernel(const int* __restrict__ dst, const int* __restrict__ rowstart,
                            int* cursor, int* __restrict__ perm, int E)
{
    int e = blockIdx.x * blockDim.x + threadIdx.x;
    if (e < E) {
        int v = dst[e];
        int p = atomicAdd(&cursor[v], 1);
        perm[rowstart[v] + p] = e;
    }
}

__global__ void gather_src_kernel(const int* __restrict__ esrc, int* perm, int E)
{
    int i = blockIdx.x * blockDim.x + threadIdx.x;
    if (i < E) perm[i] = esrc[perm[i]];
}

// ---------------- LSTM
__global__ void lstm_pre(const float* __restrict__ x, const float* __restrict__ Wf,
                         const float* __restrict__ Wb,
                         const float* bf1, const float* bf2, const float* bb1, const float* bb2,
                         float* __restrict__ xWf, float* __restrict__ xWb, int n)
{
    int gid = blockIdx.x * blockDim.x + threadIdx.x;
    if (gid >= n * 32) return;
    int nn = gid >> 5, r = gid & 31, d = r >> 4, j = r & 15;
    const float* W = (d ? Wb : Wf) + j * 192;
    const float* xr = x + (size_t)nn * 192;
    float s = 0.f;
#pragma unroll 4
    for (int k = 0; k < 192; k += 4) {
        float4 xv = *reinterpret_cast<const float4*>(xr + k);
        float4 wv = *reinterpret_cast<const float4*>(W + k);
        s += xv.x * wv.x + xv.y * wv.y + xv.z * wv.z + xv.w * wv.w;
    }
    s += d ? (bb1[j] + bb2[j]) : (bf1[j] + bf2[j]);
    int b = nn / 120, tt = nn - b * 120;
    (d ? xWb : xWf)[((size_t)b * 16 + j) * 120 + tt] = s;
}

__device__ __forceinline__ float fsigm(float x) { return __fdividef(1.f, 1.f + __expf(-x)); }
__device__ __forceinline__ float ftanh(float x) { return 1.f - __fdividef(2.f, __expf(2.f * x) + 1.f); }

template<int DIR>
__device__ void lstm_chain(const float* __restrict__ xw, const float* __restrict__ whh,
                           float* __restrict__ newF, int b)
{
    int j = threadIdx.x & 15;
    int k = j & 3;
    float4 w = *reinterpret_cast<const float4*>(whh + j * 4);
    const float* xp = xw + ((size_t)b * 16 + j) * 120;
    float h0 = 0.f, h1 = 0.f, h2 = 0.f, h3 = 0.f, cst = 0.f;
    int tb0 = DIR ? 108 : 0;
    float4 a0 = *reinterpret_cast<const float4*>(xp + tb0);
    float4 a1 = *reinterpret_cast<const float4*>(xp + tb0 + 4);
    float4 a2 = *reinterpret_cast<const float4*>(xp + tb0 + 8);
    for (int ch = 0; ch < 10; ++ch) {
        float4 b0 = a0, b1 = a1, b2 = a2;
        if (ch < 9) {
            int nt = DIR ? (96 - ch * 12) : (12 + ch * 12);
            b0 = *reinterpret_cast<const float4*>(xp + nt);
            b1 = *reinterpret_cast<const float4*>(xp + nt + 4);
            b2 = *reinterpret_cast<const float4*>(xp + nt + 8);
        }
        float zz[12] = {a0.x, a0.y, a0.z, a0.w, a1.x, a1.y, a1.z, a1.w, a2.x, a2.y, a2.z, a2.w};
        int tbase = DIR ? (108 - ch * 12) : (ch * 12);
#pragma unroll
        for (int ii = 0; ii < 12; ++ii) {
            int idx = DIR ? (11 - ii) : ii;
            float z = zz[idx] + ((w.x * h0 + w.y * h1) + (w.z * h2 + w.w * h3));
            float zi = __shfl(z, k, 16);
            float zf = __shfl(z, k + 4, 16);
            float zg = __shfl(z, k + 8, 16);
            float zo = __shfl(z, k + 12, 16);
            float ig = fsigm(zi), fg = fsigm(zf), gg = ftanh(zg), og = fsigm(zo);
            cst = fg * cst + ig * gg;
            float hn = og * ftanh(cst);
            h0 = __shfl(hn, 0, 16); h1 = __shfl(hn, 1, 16);
            h2 = __shfl(hn, 2, 16); h3 = __shfl(hn, 3, 16);
            if (j < 4) newF[((size_t)b * 120 + tbase + idx) * 8 + DIR * 4 + j] = hn;
        }
        a0 = b0; a1 = b1; a2 = b2;
    }
}

__global__ __launch_bounds__(64)
void lstm_seq2(const float* __restrict__ xWf, const float* __restrict__ xWb,
               const float* __restrict__ Whhf, const float* __restrict__ Whhb,
               float* __restrict__ newF, int B)
{
    int sub = threadIdx.x >> 4;
    int chain = blockIdx.x * 4 + sub;
    if (chain >= 2 * B) return;
    int d = chain / B;
    int b = chain - d * B;
    if (d == 0) lstm_chain<0>(xWf, Whhf, newF, b);
    else        lstm_chain<1>(xWb, Whhb, newF, b);
}

// ---------------- GraphConv combine + L1 norm: 2-edge software pipeline
__global__ __launch_bounds__(256)
void gc_combine5(const float* __restrict__ stackFT, const unsigned short* __restrict__ hw,
                 const int* __restrict__ rowstart, const int* __restrict__ csrc,
                 const float* __restrict__ rs_in,
                 const float* __restrict__ b_gc, unsigned short* __restrict__ hB, int n)
{
    int v = blockIdx.x * 4 + (threadIdx.x >> 6);
    int l = threadIdx.x & 63;
    if (v >= n) return;
    int s0 = rowstart[v], s1 = rowstart[v + 1];
    float sum0 = 0.f, sum1 = 0.f, sum2 = 0.f;

    unsigned short a0 = 0, a1 = 0, a2 = 0, b0 = 0, b1 = 0, b2 = 0;
    auto LD = [&](int i, unsigned short& x0, unsigned short& x1, unsigned short& x2) {
        const unsigned short* hr = hw + (size_t)csrc[i] * 192 + l;
        x0 = hr[0]; x1 = hr[64]; x2 = hr[128];
    };
    int i = s0;
    if (i < s1) LD(i, a0, a1, a2);
    if (i + 1 < s1) LD(i + 1, b0, b1, b2);
    for (; i + 2 < s1; i += 2) {
        unsigned short n0, n1, n2, m0 = 0, m1 = 0, m2 = 0;
        LD(i + 2, n0, n1, n2);
        if (i + 3 < s1) LD(i + 3, m0, m1, m2);
        sum0 += bf2f(a0) + bf2f(b0);
        sum1 += bf2f(a1) + bf2f(b1);
        sum2 += bf2f(a2) + bf2f(b2);
        a0 = n0; a1 = n1; a2 = n2; b0 = m0; b1 = m1; b2 = m2;
    }
    if (i < s1) { sum0 += bf2f(a0); sum1 += bf2f(a1); sum2 += bf2f(a2); }
    if (i + 1 < s1) { sum0 += bf2f(b0); sum1 += bf2f(b1); sum2 += bf2f(b2); }

    float ri = rs_in[v];
    const float* sf = stackFT + (size_t)v * 192 + l;
    float v0 = 0.5f * (sf[0]   + sum0 * ri + b_gc[l]);
    float v1 = 0.5f * (sf[64]  + sum1 * ri + b_gc[l + 64]);
    float v2 = 0.5f * (sf[128] + sum2 * ri + b_gc[l + 128]);
    float r = fabsf(v0) + fabsf(v1) + fabsf(v2);
#pragma unroll
    for (int o = 32; o; o >>= 1) r += __shfl_xor(r, o);
    float inv = __fdividef(1.f, fmaxf(r, 1e-12f));
    unsigned short* hp = hB + (size_t)v * 192 + l;
    hp[0]   = f2bf(v0 * inv);
    hp[64]  = f2bf(v1 * inv);
    hp[128] = f2bf(v2 * inv);
}

// ---------------- GATv2 F=4 (HF=64): 16 lanes/node, 2-edge pipeline, fused epilogue
__global__ __launch_bounds__(256)
void gat_edge4c(const unsigned short* __restrict__ base, // [n,192] bf16 fs|fd|res
                const float* __restrict__ attn,
                const int* __restrict__ rowstart, const int* __restrict__ csrc,
                float* __restrict__ outp, int n)
{
    int v = blockIdx.x * 16 + (threadIdx.x >> 4);
    int l = threadIdx.x & 15;
    if (v >= n) return;
    float4 at = *reinterpret_cast<const float4*>(attn + l * 4);
    ushort4 fdu = *reinterpret_cast<const ushort4*>(base + (size_t)v * 192 + 64 + l * 4);
    float fd0 = bf2f(fdu.x), fd1 = bf2f(fdu.y), fd2 = bf2f(fdu.z), fd3 = bf2f(fdu.w);
    float ac0 = 0.f, ac1 = 0.f, ac2 = 0.f, ac3 = 0.f, dn = 0.f;
    int s0 = rowstart[v], s1 = rowstart[v + 1];

    auto LD = [&](int i) -> ushort4 {
        return *reinterpret_cast<const ushort4*>(base + (size_t)csrc[i] * 192 + l * 4);
    };
    auto ACC = [&](ushort4 su) {
        float s0f = bf2f(su.x), s1f = bf2f(su.y), s2f = bf2f(su.z), s3f = bf2f(su.w);
        float e0 = s0f + fd0; e0 = fmaxf(e0, 0.2f * e0);
        float e1 = s1f + fd1; e1 = fmaxf(e1, 0.2f * e1);
        float e2 = s2f + fd2; e2 = fmaxf(e2, 0.2f * e2);
        float e3 = s3f + fd3; e3 = fmaxf(e3, 0.2f * e3);
        float p = e0 * at.x + e1 * at.y + e2 * at.z + e3 * at.w;
        float ex = __expf(p);
        ac0 += ex * s0f; ac1 += ex * s1f; ac2 += ex * s2f; ac3 += ex * s3f;
        dn += ex;
    };
    const ushort4 zu = make_ushort4(0, 0, 0, 0);
    ushort4 c0 = zu, c1 = zu;
    int i = s0;
    if (i < s1) c0 = LD(i);
    if (i + 1 < s1) c1 = LD(i + 1);
    for (; i + 2 < s1; i += 2) {
        ushort4 n0 = LD(i + 2);
        ushort4 n1 = (i + 3 < s1) ? LD(i + 3) : zu;
        ACC(c0); ACC(c1);
        c0 = n0; c1 = n1;
    }
    if (i < s1) ACC(c0);
    if (i + 1 < s1) ACC(c1);

    ushort4 ru = *reinterpret_cast<const ushort4*>(base + (size_t)v * 192 + 128 + l * 4);
    float inv = (dn > 0.f) ? __fdividef(1.f, dn) : 0.f;
    float4 o;
    o.x = fmaxf(ac0 * inv + bf2f(ru.x), 0.f);
    o.y = fmaxf(ac1 * inv + bf2f(ru.y), 0.f);
    o.z = fmaxf(ac2 * inv + bf2f(ru.z), 0.f);
    o.w = fmaxf(ac3 * inv + bf2f(ru.w), 0.f);
    *reinterpret_cast<float4*>(outp + (size_t)v * 64 + l * 4) = o;
}

// ---------------- GATv2 F=32 (HF=512): one wave per node, 8 elems/lane, 2-edge pipeline
__global__ __launch_bounds__(256)
void gat_edge32b(const unsigned short* __restrict__ base,   // [n,1024] bf16 fs|fd
                 const float* __restrict__ attn,
                 const int* __restrict__ rowstart, const int* __restrict__ csrc,
                 float* __restrict__ num, float* __restrict__ den, int n)
{
    int v = blockIdx.x * 4 + (threadIdx.x >> 6);
    int l = threadIdx.x & 63;
    if (v >= n) return;
    float at[8];
    {
        float4 aA = *reinterpret_cast<const float4*>(attn + l * 8);
        float4 aB = *reinterpret_cast<const float4*>(attn + l * 8 + 4);
        at[0] = aA.x; at[1] = aA.y; at[2] = aA.z; at[3] = aA.w;
        at[4] = aB.x; at[5] = aB.y; at[6] = aB.z; at[7] = aB.w;
    }
    float fd[8];
    {
        short8 fdu = *reinterpret_cast<const short8*>(base + (size_t)v * 1024 + 512 + l * 8);
#pragma unroll
        for (int j = 0; j < 8; ++j) fd[j] = bf2f((unsigned short)fdu[j]);
    }
    float acc[8] = {};
    float dn = 0.f;
    int s0 = rowstart[v], s1 = rowstart[v + 1];

    auto LD = [&](int i) -> short8 {
        return *reinterpret_cast<const short8*>(base + (size_t)csrc[i] * 1024 + l * 8);
    };
    auto ACC = [&](short8 su) {
        float sf[8];
        float p = 0.f;
#pragma unroll
        for (int j = 0; j < 8; ++j) {
            sf[j] = bf2f((unsigned short)su[j]);
            float e = sf[j] + fd[j];
            e = fmaxf(e, 0.2f * e);
            p += e * at[j];
        }
        p += __shfl_xor(p, 1, 4);
        p += __shfl_xor(p, 2, 4);
        float ex = __expf(p);
#pragma unroll
        for (int j = 0; j < 8; ++j) acc[j] += ex * sf[j];
        dn += ex;
    };
    const short8 z8 = {0, 0, 0, 0, 0, 0, 0, 0};
    short8 c0 = z8, c1 = z8;
    int i = s0;
    if (i < s1) c0 = LD(i);
    if (i + 1 < s1) c1 = LD(i + 1);
    for (; i + 2 < s1; i += 2) {
        short8 n0 = LD(i + 2);
        short8 n1 = (i + 3 < s1) ? LD(i + 3) : z8;
        ACC(c0); ACC(c1);
        c0 = n0; c1 = n1;
    }
    if (i < s1) ACC(c0);
    if (i + 1 < s1) ACC(c1);

    float* np = num + (size_t)v * 512 + l * 8;
    *reinterpret_cast<float4*>(np)     = make_float4(acc[0], acc[1], acc[2], acc[3]);
    *reinterpret_cast<float4*>(np + 4) = make_float4(acc[4], acc[5], acc[6], acc[7]);
    if ((l & 3) == 0) den[(size_t)v * 16 + (l >> 2)] = dn;
}

// ---------------- final classifier
__global__ void final_lin(const float* __restrict__ h1, const float* __restrict__ newF,
                          const float* __restrict__ h3, const float* __restrict__ W,
                          const float* __restrict__ bias, float* __restrict__ out, int n)
{
    int gid = blockIdx.x * blockDim.x + threadIdx.x;
    if (gid >= n * 6) return;
    int v = gid / 6, o = gid - v * 6;
    float s = bias[o];
    const float* a = h1 + (size_t)v * 64;
#pragma unroll 8
    for (int r = 0; r < 64; ++r) s += a[r] * W[r * 6 + o];
    const float* b = newF + (size_t)v * 8;
#pragma unroll
    for (int r = 0; r < 8; ++r) s += b[r] * W[(64 + r) * 6 + o];
    const float* c = h3 + (size_t)v * 64;
#pragma unroll 8
    for (int r = 0; r < 64; ++r) s += c[r] * W[(72 + r) * 6 + o];
    out[gid] = s;
}

// ----------------------------------------------------------------------------
extern "C" void kernel_launch(void* const* d_in, const int* in_sizes, int n_in,
                              void* d_out, int out_size, void* d_ws, size_t ws_size,
                              hipStream_t stream)
{
    const float* text   = (const float*)d_in[0];
    const float* audio  = (const float*)d_in[1];
    const float* vision = (const float*)d_in[2];
    const int*   esrc   = (const int*)d_in[3];
    const int*   edst   = (const int*)d_in[4];
    const float* W_audio = (const float*)d_in[5];  const float* b_audio = (const float*)d_in[6];
    const float* W_vision= (const float*)d_in[7];  const float* b_vision= (const float*)d_in[8];
    const float* W_text  = (const float*)d_in[9];  const float* b_text  = (const float*)d_in[10];
    const float* Wih_f = (const float*)d_in[11]; const float* Whh_f = (const float*)d_in[12];
    const float* bih_f = (const float*)d_in[13]; const float* bhh_f = (const float*)d_in[14];
    const float* Wih_b = (const float*)d_in[15]; const float* Whh_b = (const float*)d_in[16];
    const float* bih_b = (const float*)d_in[17]; const float* bhh_b = (const float*)d_in[18];
    const float* W_gc  = (const float*)d_in[19]; const float* b_gc  = (const float*)d_in[20];
    const float* Wsrc2 = (const float*)d_in[21]; const float* bsrc2 = (const float*)d_in[22];
    const float* Wdst2 = (const float*)d_in[23]; const float* bdst2 = (const float*)d_in[24];
    const float* attn2 = (const float*)d_in[25]; const float* Wres2 = (const float*)d_in[26];
    const float* Wsrc0 = (const float*)d_in[27]; const float* bsrc0 = (const float*)d_in[28];
    const float* Wdst0 = (const float*)d_in[29]; const float* bdst0 = (const float*)d_in[30];
    const float* attn0 = (const float*)d_in[31]; const float* Wres0 = (const float*)d_in[32];
    const float* Wsrc1 = (const float*)d_in[33]; const float* bsrc1 = (const float*)d_in[34];
    const float* Wdst1 = (const float*)d_in[35]; const float* bdst1 = (const float*)d_in[36];
    const float* attn1 = (const float*)d_in[37]; const float* Wres1 = (const float*)d_in[38];
    const float* W_lin = (const float*)d_in[39]; const float* b_lin = (const float*)d_in[40];
    float* out = (float*)d_out;

    const int n = in_sizes[0] / 1024;   // 12000
    const int E = in_sizes[3];          // 192000
    const int B = n / 120;              // 100

    // ---- workspace carve (256B aligned)
    char* p = (char*)d_ws;
    auto alloc_f = [&](size_t cnt) { float* r = (float*)p; p += ((cnt * 4 + 255) / 256) * 256; return r; };
    auto alloc_h = [&](size_t cnt) { unsigned short* r = (unsigned short*)p; p += ((cnt * 2 + 255) / 256) * 256; return r; };
    auto alloc_i = [&](size_t cnt) { int* r = (int*)p; p += ((cnt * 4 + 255) / 256) * 256; return r; };
    float*          stackFT = alloc_f((size_t)n * 192);
    unsigned short* stackBF = alloc_h((size_t)n * 192);
    unsigned short* hbufBF  = alloc_h((size_t)n * 192);
    unsigned short* encW    = alloc_h(163840);
    float* xWf     = alloc_f((size_t)n * 16);
    float* xWb     = alloc_f((size_t)n * 16);
    float* newF    = alloc_f((size_t)n * 8);
    float* big0    = alloc_f((size_t)n * 512);
    float* big1    = alloc_f((size_t)n * 512);
    float* big2    = alloc_f((size_t)n * 512);
    float* den     = alloc_f((size_t)n * 16);
    float* h3      = alloc_f((size_t)n * 64);
    float* h1s     = alloc_f((size_t)n * 64);   // hosts packed weights until gat1 edge writes it
    float* rs_out  = alloc_f(n);
    float* rs_in   = alloc_f(n);
    int* zero_base = alloc_i((size_t)3 * n);
    int* degout = zero_base;
    int* degin  = zero_base + n;
    int* cursor = zero_base + 2 * n;
    int* rowstart = alloc_i((size_t)n + 1);
    int* perm     = alloc_i((size_t)E);
    if ((size_t)(p - (char*)d_ws) > ws_size) return;

    // packed weights live in h1s (dead until gat1 edge): 466944 shorts + 1408 floats
    unsigned short* Wall = (unsigned short*)h1s;
    float* ball = h1s + 240000;
    const unsigned short* Wp_gc = Wall;
    const unsigned short* Wp_g2 = Wall + 36864;
    const unsigned short* Wp_g0 = Wall + 73728;
    const unsigned short* Wp_r0 = Wall + 270336;
    const unsigned short* Wp_g1 = Wall + 368640;
    const float* bp_g2 = ball;
    const float* bp_g0 = ball + 192;
    const float* bp_g1 = ball + 1216;

    // ---- graph preprocessing + one fused weight-pack
    hipMemsetAsync(zero_base, 0, (size_t)3 * n * 4, stream);
    pack_all<<<(468352 + 255) / 256, 256, 0, stream>>>(
        W_text, W_audio, W_vision, W_gc,
        Wsrc2, Wdst2, Wres2, bsrc2, bdst2,
        Wsrc0, Wdst0, bsrc0, bdst0, Wres0,
        Wsrc1, Wdst1, Wres1, bsrc1, bdst1,
        (_Float16*)encW, Wall, ball);
    deg_kernel<<<(E + 255) / 256, 256, 0, stream>>>(esrc, edst, degout, degin, E);
    scan_kernel<<<1, 1024, 0, stream>>>(degin, degout, rowstart, rs_out, rs_in, n);
    perm_kernel<<<(E + 255) / 256, 256, 0, stream>>>(edst, rowstart, cursor, perm, E);
    gather_src_kernel<<<(E + 255) / 256, 256, 0, stream>>>(esrc, perm, E);
    const int* csrc = perm;

    auto gemm = [&](auto mf_tag, auto om_tag, const unsigned short* A, const unsigned short* Bm,
                    const float* bias, const float* rsc, void* Cp,
                    const float* fnum, const float* fden, int M, int Nb, int K, int ldc) {
        constexpr int MF = decltype(mf_tag)::value;
        constexpr int OM = decltype(om_tag)::value;
        dim3 grid((M + 64 * MF - 1) / (64 * MF), Nb / 64);
        gemm_v7<MF, OM><<<grid, 256, 0, stream>>>(A, Bm, bias, rsc, Cp, fnum, fden, M, Nb, K, ldc);
    };
    using I1 = std::integral_constant<int, 1>;
    using I2 = std::integral_constant<int, 2>;
    using O1 = std::integral_constant<int, 1>;
    using O2 = std::integral_constant<int, 2>;

    // ---- modality encoders (barrier-free f16 MFMA, LDS-transposed epilogue)
    {
        int waves = 3 * (n >> 4);
        enc_f16v6<<<(waves * 64 + 255) / 256, 256, 0, stream>>>(
            text, audio, vision, (const _Float16*)encW,
            b_text, b_audio, b_vision, stackFT, stackBF, n);
    }

    // ---- BiLSTM
    lstm_pre<<<(n * 32 + 255) / 256, 256, 0, stream>>>(stackFT, Wih_f, Wih_b,
                                                       bih_f, bhh_f, bih_b, bhh_b, xWf, xWb, n);
    lstm_seq2<<<(2 * B + 3) / 4, 64, 0, stream>>>(xWf, xWb, Whh_f, Whh_b, newF, B);

    // ---- GraphConv imputation + L1 norm -> hbufBF (bf16)
    gemm(I1{}, O1{}, stackBF, Wp_gc, nullptr, rs_out, big0, nullptr, nullptr, n, 192, 192, 192);
    gc_combine5<<<(n + 3) / 4, 256, 0, stream>>>(stackFT, (const unsigned short*)big0,
                                                 rowstart, csrc, rs_in, b_gc, hbufBF, n);

    // ---- gat2: packed src|dst|res GEMM -> big0 bf16 [n,192], fused edge -> h3
    gemm(I1{}, O1{}, hbufBF, Wp_g2, bp_g2, nullptr, big0, nullptr, nullptr, n, 192, 192, 192);
    gat_edge4c<<<(n + 15) / 16, 256, 0, stream>>>((const unsigned short*)big0, attn2, rowstart, csrc, h3, n);

    // ---- gat0: packed src|dst GEMM -> big0 bf16 [n,1024]; edge -> big2/den;
    //            res GEMM with fused finalize -> big1 bf16 [n,512]
    gemm(I2{}, O1{}, hbufBF, Wp_g0, bp_g0, nullptr, big0, nullptr, nullptr, n, 1024, 192, 1024);
    gat_edge32b<<<(n + 3) / 4, 256, 0, stream>>>((const unsigned short*)big0, attn0, rowstart, csrc, big2, den, n);
    gemm(I1{}, O2{}, hbufBF, Wp_r0, nullptr, nullptr, big1, big2, den, n, 512, 192, 512);

    // ---- gat1: packed src|dst|res GEMM (A = big1 bf16 [n,512]) -> big0 bf16 [n,192], fused edge -> h1s
    gemm(I1{}, O1{}, (const unsigned short*)big1, Wp_g1, bp_g1, nullptr, big0, nullptr, nullptr, n, 192, 512, 192);
    gat_edge4c<<<(n + 15) / 16, 256, 0, stream>>>((const unsigned short*)big0, attn1, rowstart, csrc, h1s, n);

    // ---- final classifier
    final_lin<<<(n * 6 + 255) / 256, 256, 0, stream>>>(h1s, newF, h3, W_lin, b_lin, out, n);
}

// Round 14
// 331.447 us; speedup vs baseline: 1.0817x; 1.0798x over previous
//
#include <hip/hip_runtime.h>

typedef __attribute__((ext_vector_type(8))) short short8;
typedef __attribute__((ext_vector_type(4))) float f32x4;
typedef _Float16 half8v __attribute__((ext_vector_type(8)));

__device__ __forceinline__ unsigned short f2bf(float f) {
    unsigned u = __float_as_uint(f);
    u += 0x7FFFu + ((u >> 16) & 1u);
    return (unsigned short)(u >> 16);
}
__device__ __forceinline__ float bf2f(unsigned short h) {
    return __uint_as_float((unsigned)h << 16);
}

// =====================================================================
// gemm_v7: C[M,Nb] = A[M,K](bf16) @ B[K,Nb](bf16, pre-packed) (+bias)(*rowscale)
// OUTMODE: 0=f32, 1=bf16, 2=bf16+fused GAT finalize, 3=LSTM transposed scatter
//   (OUTMODE 3: Cv = xWf, fin_num = xWb; cols 0-15 -> fwd gate j, 16-31 -> bwd)
template<int MF, int OUTMODE>
__global__ __launch_bounds__(256)
void gemm_v7(const unsigned short* __restrict__ A, const unsigned short* __restrict__ B,
             const float* __restrict__ bias, const float* __restrict__ rowscale,
             void* __restrict__ Cv, const float* __restrict__ fin_num,
             const float* __restrict__ fin_den,
             int M, int Nb, int K, int ldc)
{
    __shared__ alignas(16) unsigned short As[MF * 64 * 32];
    __shared__ alignas(16) unsigned short Bs[4 * 64 * 8];
    const int t = threadIdx.x;
    const int w = t >> 6, l = t & 63;
    const int r16 = l & 15, kg = l >> 4;
    const int row0 = blockIdx.x * (64 * MF);
    const int col0 = blockIdx.y * 64;
    const int bcol = t & 63, bkg = t >> 6;

    f32x4 acc[MF][4] = {};
    const short8 z8 = {0, 0, 0, 0, 0, 0, 0, 0};

    int srow[MF], sch[MF];
    bool va[MF];
    const unsigned short* aptr[MF];
#pragma unroll
    for (int it = 0; it < MF; ++it) {
        int idx = it * 256 + t;
        srow[it] = idx >> 2; sch[it] = idx & 3;
        int gm = row0 + srow[it];
        va[it] = gm < M;
        aptr[it] = A + (size_t)gm * K + sch[it] * 8;
    }
    const unsigned short* bptr = B + (size_t)(bkg * 8) * Nb + col0 + bcol;

    short8 pa[MF];
    unsigned short pbv[8];
#pragma unroll
    for (int it = 0; it < MF; ++it)
        pa[it] = va[it] ? *reinterpret_cast<const short8*>(aptr[it]) : z8;
#pragma unroll
    for (int j = 0; j < 8; ++j) pbv[j] = bptr[(size_t)j * Nb];

    for (int k0 = 0; k0 < K; k0 += 32) {
#pragma unroll
        for (int it = 0; it < MF; ++it)
            *reinterpret_cast<short8*>(&As[srow[it] * 32 + sch[it] * 8]) = pa[it];
        {
            short8 hv;
#pragma unroll
            for (int j = 0; j < 8; ++j) hv[j] = (short)pbv[j];
            *reinterpret_cast<short8*>(&Bs[bkg * 512 + bcol * 8]) = hv;
        }
        __syncthreads();
        if (k0 + 32 < K) {
#pragma unroll
            for (int it = 0; it < MF; ++it)
                pa[it] = va[it] ? *reinterpret_cast<const short8*>(aptr[it] + k0 + 32) : z8;
#pragma unroll
            for (int j = 0; j < 8; ++j) pbv[j] = bptr[(size_t)(k0 + 32 + j) * Nb];
        }
        short8 af[MF];
#pragma unroll
        for (int mi = 0; mi < MF; ++mi)
            af[mi] = *reinterpret_cast<const short8*>(&As[((w * MF + mi) * 16 + r16) * 32 + kg * 8]);
#pragma unroll
        for (int ni = 0; ni < 4; ++ni) {
            short8 bf = *reinterpret_cast<const short8*>(&Bs[kg * 512 + (ni * 16 + r16) * 8]);
#pragma unroll
            for (int mi = 0; mi < MF; ++mi)
                acc[mi][ni] = __builtin_amdgcn_mfma_f32_16x16x32_bf16(af[mi], bf, acc[mi][ni], 0, 0, 0);
        }
        __syncthreads();
    }
#pragma unroll
    for (int mi = 0; mi < MF; ++mi)
#pragma unroll
        for (int ni = 0; ni < 4; ++ni) {
            int col = col0 + ni * 16 + r16;
            float bv = bias ? bias[col] : 0.f;
#pragma unroll
            for (int r = 0; r < 4; ++r) {
                int gm = row0 + (w * MF + mi) * 16 + kg * 4 + r;
                if (gm < M) {
                    float val = acc[mi][ni][r] + bv;
                    if (rowscale) val *= rowscale[gm];
                    size_t idx = (size_t)gm * ldc + col;
                    if (OUTMODE == 0) {
                        ((float*)Cv)[idx] = val;
                    } else if (OUTMODE == 1) {
                        ((unsigned short*)Cv)[idx] = f2bf(val);
                    } else if (OUTMODE == 2) {
                        float d = fin_den[(size_t)gm * 16 + (col >> 5)];
                        float inv = (d > 0.f) ? __fdividef(1.f, d) : 0.f;
                        float o = fmaxf(fin_num[idx] * inv + val, 0.f);
                        ((unsigned short*)Cv)[idx] = f2bf(o);
                    } else {   // OUTMODE 3: LSTM transposed scatter
                        if (col < 32) {
                            int d = col >> 4, j = col & 15;
                            int bb = gm / 120, tt = gm - bb * 120;
                            float* dst = d ? (float*)fin_num : (float*)Cv;
                            dst[((size_t)bb * 16 + j) * 120 + tt] = val;
                        }
                    }
                }
            }
        }
}

// =====================================================================
// encoder v6: barrier-free f16 MFMA (frag-packed weights, direct A),
// LDS-transposed epilogue. (At its access-pattern floor; unchanged.)
__global__ __launch_bounds__(256)
void enc_f16v6(const float* __restrict__ text, const float* __restrict__ audio, const float* __restrict__ vision,
               const _Float16* __restrict__ Wf16,
               const float* __restrict__ bt, const float* __restrict__ ba, const float* __restrict__ bv,
               float* __restrict__ Cf, unsigned short* __restrict__ Cb, int M)
{
    __shared__ float tbuf[4][16][68];
    const int gw = (blockIdx.x * blockDim.x + threadIdx.x) >> 6;
    const int wib = threadIdx.x >> 6;
    const int l = threadIdx.x & 63;
    const int tpm = M >> 4;
    if (gw >= 3 * tpm) return;
    const int z = gw / tpm;
    const int tidx = gw - z * tpm;
    const float* A  = (z == 0) ? text : (z == 1) ? audio : vision;
    const _Float16* Wp = Wf16 + ((z == 0) ? 0 : (z == 1) ? 65536 : 98304) + l * 8;
    const float* bb = (z == 0) ? bt : (z == 1) ? ba : bv;
    const int KC = (z == 1) ? 16 : 32;

    const float* ap = A + (size_t)(tidx * 16 + (l & 15)) * (KC * 32) + (l >> 4) * 8;

    f32x4 acc0 = {}, acc1 = {}, acc2 = {}, acc3 = {};
    float4 na0 = *reinterpret_cast<const float4*>(ap);
    float4 na1 = *reinterpret_cast<const float4*>(ap + 4);
    half8v nb0 = *reinterpret_cast<const half8v*>(Wp);
    half8v nb1 = *reinterpret_cast<const half8v*>(Wp + 512);
    half8v nb2 = *reinterpret_cast<const half8v*>(Wp + 1024);
    half8v nb3 = *reinterpret_cast<const half8v*>(Wp + 1536);

    for (int kc = 0; kc < KC; ++kc) {
        float4 ca0 = na0, ca1 = na1;
        half8v cb0 = nb0, cb1 = nb1, cb2 = nb2, cb3 = nb3;
        if (kc + 1 < KC) {
            const float* apn = ap + (kc + 1) * 32;
            na0 = *reinterpret_cast<const float4*>(apn);
            na1 = *reinterpret_cast<const float4*>(apn + 4);
            const _Float16* wpn = Wp + (size_t)(kc + 1) * 2048;
            nb0 = *reinterpret_cast<const half8v*>(wpn);
            nb1 = *reinterpret_cast<const half8v*>(wpn + 512);
            nb2 = *reinterpret_cast<const half8v*>(wpn + 1024);
            nb3 = *reinterpret_cast<const half8v*>(wpn + 1536);
        }
        half8v af;
        af[0] = (_Float16)ca0.x; af[1] = (_Float16)ca0.y;
        af[2] = (_Float16)ca0.z; af[3] = (_Float16)ca0.w;
        af[4] = (_Float16)ca1.x; af[5] = (_Float16)ca1.y;
        af[6] = (_Float16)ca1.z; af[7] = (_Float16)ca1.w;
        acc0 = __builtin_amdgcn_mfma_f32_16x16x32_f16(af, cb0, acc0, 0, 0, 0);
        acc1 = __builtin_amdgcn_mfma_f32_16x16x32_f16(af, cb1, acc1, 0, 0, 0);
        acc2 = __builtin_amdgcn_mfma_f32_16x16x32_f16(af, cb2, acc2, 0, 0, 0);
        acc3 = __builtin_amdgcn_mfma_f32_16x16x32_f16(af, cb3, acc3, 0, 0, 0);
    }

    const int r16 = l & 15, hi = l >> 4;
    float* tl = &tbuf[wib][0][0];
#pragma unroll
    for (int cg = 0; cg < 4; ++cg) {
        f32x4 a = (cg == 0) ? acc0 : (cg == 1) ? acc1 : (cg == 2) ? acc2 : acc3;
        int col = cg * 16 + r16;
        float bvv = bb[col];
#pragma unroll
        for (int r = 0; r < 4; ++r)
            tl[(hi * 4 + r) * 68 + col] = a[r] + bvv;
    }
#pragma unroll
    for (int r = 0; r < 16; ++r) {
        float val = tl[r * 68 + l];
        size_t idx = (size_t)(tidx * 16 + r) * 192 + z * 64 + l;
        Cf[idx] = val;
        Cb[idx] = f2bf(val);
    }
}

// =====================================================================
// one fused weight-pack kernel (now also packs LSTM input weights+biases)
// Wall (shorts): gc@0 | g2@36864 | g0@73728 | r0@270336 | g1@368640 | lstm@466944(12288)
// ball (f32): g2b@0(192) | g0b@192(1024) | g1b@1216(192) | lstmb@1408(32)
__global__ void pack_all(const float* __restrict__ Wt, const float* __restrict__ Wa, const float* __restrict__ Wv,
                         const float* __restrict__ Wgc,
                         const float* __restrict__ Ws2, const float* __restrict__ Wd2, const float* __restrict__ Wr2,
                         const float* __restrict__ bs2, const float* __restrict__ bd2,
                         const float* __restrict__ Ws0, const float* __restrict__ Wd0,
                         const float* __restrict__ bs0, const float* __restrict__ bd0,
                         const float* __restrict__ Wr0,
                         const float* __restrict__ Ws1, const float* __restrict__ Wd1, const float* __restrict__ Wr1,
                         const float* __restrict__ bs1, const float* __restrict__ bd1,
                         const float* __restrict__ Wihf, const float* __restrict__ Wihb,
                         const float* __restrict__ bihf, const float* __restrict__ bhhf,
                         const float* __restrict__ bihb, const float* __restrict__ bhhb,
                         _Float16* __restrict__ encW, unsigned short* __restrict__ Wall, float* __restrict__ ball)
{
    int gid = blockIdx.x * blockDim.x + threadIdx.x;
    if (gid < 163840) {
        const float* Wsrcp;
        int base;
        if (gid < 65536)      { base = 0;     Wsrcp = Wt; }
        else if (gid < 98304) { base = 65536; Wsrcp = Wa; }
        else                  { base = 98304; Wsrcp = Wv; }
        int i = gid - base;
        int kc = i >> 11, r = i & 2047;
        int cg = r >> 9, lane = (r >> 3) & 63, j = r & 7;
        int k = kc * 32 + (lane >> 4) * 8 + j;
        int col = cg * 16 + (lane & 15);
        encW[gid] = (_Float16)Wsrcp[k * 64 + col];
    }
    if (gid < 36864) {
        Wall[gid] = f2bf(Wgc[gid]);
    } else if (gid < 73728) {
        int i = gid - 36864, k = i / 192, c = i - k * 192;
        float v = (c < 64) ? Ws2[k * 64 + c] : (c < 128) ? Wd2[k * 64 + c - 64] : Wr2[k * 64 + c - 128];
        Wall[gid] = f2bf(v);
    } else if (gid < 270336) {
        int i = gid - 73728, k = i >> 10, c = i & 1023;
        float v = (c < 512) ? Ws0[k * 512 + c] : Wd0[k * 512 + c - 512];
        Wall[gid] = f2bf(v);
    } else if (gid < 368640) {
        Wall[gid] = f2bf(Wr0[gid - 270336]);
    } else if (gid < 466944) {
        int i = gid - 368640, k = i / 192, c = i - k * 192;
        float v = (c < 64) ? Ws1[k * 64 + c] : (c < 128) ? Wd1[k * 64 + c - 64] : Wr1[k * 64 + c - 128];
        Wall[gid] = f2bf(v);
    } else if (gid < 479232) {
        int i = gid - 466944, k = i >> 6, c = i & 63;   // W_lstm[k][c], [192][64]
        float v = (c < 16) ? Wihf[c * 192 + k] : (c < 32) ? Wihb[(c - 16) * 192 + k] : 0.f;
        Wall[gid] = f2bf(v);
    } else if (gid < 480672) {
        int i = gid - 479232;
        float v;
        if (i < 192)       v = (i < 64) ? bs2[i] : (i < 128) ? bd2[i - 64] : 0.f;
        else if (i < 1216) { int j = i - 192; v = (j < 512) ? bs0[j] : bd0[j - 512]; }
        else if (i < 1408) { int j = i - 1216; v = (j < 64) ? bs1[j] : (j < 128) ? bd1[j - 64] : 0.f; }
        else               { int j = i - 1408; v = (j < 16) ? (bihf[j] + bhhf[j]) : (bihb[j - 16] + bhhb[j - 16]); }
        ball[i] = v;
    }
}

// ---------------- graph preprocessing
__global__ void deg_kernel(const int* __restrict__ src, const int* __restrict__ dst,
                           int* degout, int* degin, int E)
{
    int e = blockIdx.x * blockDim.x + threadIdx.x;
    if (e < E) {
        atomicAdd(&degout[src[e]], 1);
        atomicAdd(&degin[dst[e]], 1);
    }
}

__global__ __launch_bounds__(1024)
void scan_kernel(const int* __restrict__ degin, const int* __restrict__ degout,
                 int* __restrict__ rowstart, float* __restrict__ rso, float* __restrict__ rsi, int n)
{
    __shared__ int part[1024];
    int t = threadIdx.x;
    int chunk = (n + 1023) / 1024;
    int s = 0;
    for (int i = 0; i < chunk; ++i) {
        int idx = t * chunk + i;
        if (idx < n) s += degin[idx];
    }
    part[t] = s;
    __syncthreads();
    for (int o = 1; o < 1024; o <<= 1) {
        int v = (t >= o) ? part[t - o] : 0;
        __syncthreads();
        part[t] += v;
        __syncthreads();
    }
    int run = (t > 0) ? part[t - 1] : 0;
    for (int i = 0; i < chunk; ++i) {
        int idx = t * chunk + i;
        if (idx < n) {
            rowstart[idx] = run; run += degin[idx];
            rso[idx] = rsqrtf((float)max(degout[idx], 1));
            rsi[idx] = rsqrtf((float)max(degin[idx], 1));
        }
    }
    if (t == 1023) rowstart[n] = part[1023];
}

__global__ void perm_kernel(const int* __restrict__ dst, const int* __restrict__ rowstart,
                            int* cursor, int* __restrict__ perm, int E)
{
    int e = blockIdx.x * blockDim.x + threadIdx.x;
    if (e < E) {
        int v = dst[e];
        int p = atomicAdd(&cursor[v], 1);
        perm[rowstart[v] + p] = e;
    }
}

__global__ void gather_src_kernel(const int* __restrict__ esrc, int* perm, int E)
{
    int i = blockIdx.x * blockDim.x + threadIdx.x;
    if (i < E) perm[i] = esrc[perm[i]];
}

// ---------------- LSTM (sequential part only; xW comes from the MFMA GEMM)
__device__ __forceinline__ float fsigm(float x) { return __fdividef(1.f, 1.f + __expf(-x)); }
__device__ __forceinline__ float ftanh(float x) { return 1.f - __fdividef(2.f, __expf(2.f * x) + 1.f); }

template<int DIR>
__device__ void lstm_chain(const float* __restrict__ xw, const float* __restrict__ whh,
                           float* __restrict__ newF, int b)
{
    int j = threadIdx.x & 15;
    int k = j & 3;
    float4 w = *reinterpret_cast<const float4*>(whh + j * 4);
    const float* xp = xw + ((size_t)b * 16 + j) * 120;
    float h0 = 0.f, h1 = 0.f, h2 = 0.f, h3 = 0.f, cst = 0.f;
    int tb0 = DIR ? 108 : 0;
    float4 a0 = *reinterpret_cast<const float4*>(xp + tb0);
    float4 a1 = *reinterpret_cast<const float4*>(xp + tb0 + 4);
    float4 a2 = *reinterpret_cast<const float4*>(xp + tb0 + 8);
    for (int ch = 0; ch < 10; ++ch) {
        float4 b0 = a0, b1 = a1, b2 = a2;
        if (ch < 9) {
            int nt = DIR ? (96 - ch * 12) : (12 + ch * 12);
            b0 = *reinterpret_cast<const float4*>(xp + nt);
            b1 = *reinterpret_cast<const float4*>(xp + nt + 4);
            b2 = *reinterpret_cast<const float4*>(xp + nt + 8);
        }
        float zz[12] = {a0.x, a0.y, a0.z, a0.w, a1.x, a1.y, a1.z, a1.w, a2.x, a2.y, a2.z, a2.w};
        int tbase = DIR ? (108 - ch * 12) : (ch * 12);
#pragma unroll
        for (int ii = 0; ii < 12; ++ii) {
            int idx = DIR ? (11 - ii) : ii;
            float z = zz[idx] + ((w.x * h0 + w.y * h1) + (w.z * h2 + w.w * h3));
            float zi = __shfl(z, k, 16);
            float zf = __shfl(z, k + 4, 16);
            float zg = __shfl(z, k + 8, 16);
            float zo = __shfl(z, k + 12, 16);
            float ig = fsigm(zi), fg = fsigm(zf), gg = ftanh(zg), og = fsigm(zo);
            cst = fg * cst + ig * gg;
            float hn = og * ftanh(cst);
            h0 = __shfl(hn, 0, 16); h1 = __shfl(hn, 1, 16);
            h2 = __shfl(hn, 2, 16); h3 = __shfl(hn, 3, 16);
            if (j < 4) newF[((size_t)b * 120 + tbase + idx) * 8 + DIR * 4 + j] = hn;
        }
        a0 = b0; a1 = b1; a2 = b2;
    }
}

__global__ __launch_bounds__(64)
void lstm_seq2(const float* __restrict__ xWf, const float* __restrict__ xWb,
               const float* __restrict__ Whhf, const float* __restrict__ Whhb,
               float* __restrict__ newF, int B)
{
    int sub = threadIdx.x >> 4;
    int chain = blockIdx.x * 4 + sub;
    if (chain >= 2 * B) return;
    int d = chain / B;
    int b = chain - d * B;
    if (d == 0) lstm_chain<0>(xWf, Whhf, newF, b);
    else        lstm_chain<1>(xWb, Whhb, newF, b);
}

// ---------------- GraphConv combine + L1 norm: 2-edge software pipeline
__global__ __launch_bounds__(256)
void gc_combine5(const float* __restrict__ stackFT, const unsigned short* __restrict__ hw,
                 const int* __restrict__ rowstart, const int* __restrict__ csrc,
                 const float* __restrict__ rs_in,
                 const float* __restrict__ b_gc, unsigned short* __restrict__ hB, int n)
{
    int v = blockIdx.x * 4 + (threadIdx.x >> 6);
    int l = threadIdx.x & 63;
    if (v >= n) return;
    int s0 = rowstart[v], s1 = rowstart[v + 1];
    float sum0 = 0.f, sum1 = 0.f, sum2 = 0.f;

    unsigned short a0 = 0, a1 = 0, a2 = 0, b0 = 0, b1 = 0, b2 = 0;
    auto LD = [&](int i, unsigned short& x0, unsigned short& x1, unsigned short& x2) {
        const unsigned short* hr = hw + (size_t)csrc[i] * 192 + l;
        x0 = hr[0]; x1 = hr[64]; x2 = hr[128];
    };
    int i = s0;
    if (i < s1) LD(i, a0, a1, a2);
    if (i + 1 < s1) LD(i + 1, b0, b1, b2);
    for (; i + 2 < s1; i += 2) {
        unsigned short n0, n1, n2, m0 = 0, m1 = 0, m2 = 0;
        LD(i + 2, n0, n1, n2);
        if (i + 3 < s1) LD(i + 3, m0, m1, m2);
        sum0 += bf2f(a0) + bf2f(b0);
        sum1 += bf2f(a1) + bf2f(b1);
        sum2 += bf2f(a2) + bf2f(b2);
        a0 = n0; a1 = n1; a2 = n2; b0 = m0; b1 = m1; b2 = m2;
    }
    if (i < s1) { sum0 += bf2f(a0); sum1 += bf2f(a1); sum2 += bf2f(a2); }
    if (i + 1 < s1) { sum0 += bf2f(b0); sum1 += bf2f(b1); sum2 += bf2f(b2); }

    float ri = rs_in[v];
    const float* sf = stackFT + (size_t)v * 192 + l;
    float v0 = 0.5f * (sf[0]   + sum0 * ri + b_gc[l]);
    float v1 = 0.5f * (sf[64]  + sum1 * ri + b_gc[l + 64]);
    float v2 = 0.5f * (sf[128] + sum2 * ri + b_gc[l + 128]);
    float r = fabsf(v0) + fabsf(v1) + fabsf(v2);
#pragma unroll
    for (int o = 32; o; o >>= 1) r += __shfl_xor(r, o);
    float inv = __fdividef(1.f, fmaxf(r, 1e-12f));
    unsigned short* hp = hB + (size_t)v * 192 + l;
    hp[0]   = f2bf(v0 * inv);
    hp[64]  = f2bf(v1 * inv);
    hp[128] = f2bf(v2 * inv);
}

// ---------------- GATv2 F=4 (HF=64): 16 lanes/node, 4-edge pipeline, fused epilogue
__global__ __launch_bounds__(256)
void gat_edge4c(const unsigned short* __restrict__ base, // [n,192] bf16 fs|fd|res
                const float* __restrict__ attn,
                const int* __restrict__ rowstart, const int* __restrict__ csrc,
                float* __restrict__ outp, int n)
{
    int v = blockIdx.x * 16 + (threadIdx.x >> 4);
    int l = threadIdx.x & 15;
    if (v >= n) return;
    float4 at = *reinterpret_cast<const float4*>(attn + l * 4);
    ushort4 fdu = *reinterpret_cast<const ushort4*>(base + (size_t)v * 192 + 64 + l * 4);
    float fd0 = bf2f(fdu.x), fd1 = bf2f(fdu.y), fd2 = bf2f(fdu.z), fd3 = bf2f(fdu.w);
    float ac0 = 0.f, ac1 = 0.f, ac2 = 0.f, ac3 = 0.f, dn = 0.f;
    int s0 = rowstart[v], s1 = rowstart[v + 1];

    auto LD = [&](int i) -> ushort4 {
        return *reinterpret_cast<const ushort4*>(base + (size_t)csrc[i] * 192 + l * 4);
    };
    auto ACC = [&](ushort4 su) {
        float s0f = bf2f(su.x), s1f = bf2f(su.y), s2f = bf2f(su.z), s3f = bf2f(su.w);
        float e0 = s0f + fd0; e0 = fmaxf(e0, 0.2f * e0);
        float e1 = s1f + fd1; e1 = fmaxf(e1, 0.2f * e1);
        float e2 = s2f + fd2; e2 = fmaxf(e2, 0.2f * e2);
        float e3 = s3f + fd3; e3 = fmaxf(e3, 0.2f * e3);
        float p = e0 * at.x + e1 * at.y + e2 * at.z + e3 * at.w;
        float ex = __expf(p);
        ac0 += ex * s0f; ac1 += ex * s1f; ac2 += ex * s2f; ac3 += ex * s3f;
        dn += ex;
    };
    const ushort4 zu = make_ushort4(0, 0, 0, 0);
    ushort4 c0 = zu, c1 = zu, c2 = zu, c3 = zu;
    int i = s0;
    if (i     < s1) c0 = LD(i);
    if (i + 1 < s1) c1 = LD(i + 1);
    if (i + 2 < s1) c2 = LD(i + 2);
    if (i + 3 < s1) c3 = LD(i + 3);
    for (; i + 4 < s1; i += 4) {
        ushort4 n0 = LD(i + 4);
        ushort4 n1 = (i + 5 < s1) ? LD(i + 5) : zu;
        ushort4 n2 = (i + 6 < s1) ? LD(i + 6) : zu;
        ushort4 n3 = (i + 7 < s1) ? LD(i + 7) : zu;
        ACC(c0); ACC(c1); ACC(c2); ACC(c3);
        c0 = n0; c1 = n1; c2 = n2; c3 = n3;
    }
    if (i     < s1) ACC(c0);
    if (i + 1 < s1) ACC(c1);
    if (i + 2 < s1) ACC(c2);
    if (i + 3 < s1) ACC(c3);

    ushort4 ru = *reinterpret_cast<const ushort4*>(base + (size_t)v * 192 + 128 + l * 4);
    float inv = (dn > 0.f) ? __fdividef(1.f, dn) : 0.f;
    float4 o;
    o.x = fmaxf(ac0 * inv + bf2f(ru.x), 0.f);
    o.y = fmaxf(ac1 * inv + bf2f(ru.y), 0.f);
    o.z = fmaxf(ac2 * inv + bf2f(ru.z), 0.f);
    o.w = fmaxf(ac3 * inv + bf2f(ru.w), 0.f);
    *reinterpret_cast<float4*>(outp + (size_t)v * 64 + l * 4) = o;
}

// ---------------- GATv2 F=32 (HF=512): one wave per node, 8 elems/lane, 4-edge pipeline
__global__ __launch_bounds__(256)
void gat_edge32b(const unsigned short* __restrict__ base,   // [n,1024] bf16 fs|fd
                 const float* __restrict__ attn,
                 const int* __restrict__ rowstart, const int* __restrict__ csrc,
                 float* __restrict__ num, float* __restrict__ den, int n)
{
    int v = blockIdx.x * 4 + (threadIdx.x >> 6);
    int l = threadIdx.x & 63;
    if (v >= n) return;
    float at[8];
    {
        float4 aA = *reinterpret_cast<const float4*>(attn + l * 8);
        float4 aB = *reinterpret_cast<const float4*>(attn + l * 8 + 4);
        at[0] = aA.x; at[1] = aA.y; at[2] = aA.z; at[3] = aA.w;
        at[4] = aB.x; at[5] = aB.y; at[6] = aB.z; at[7] = aB.w;
    }
    float fd[8];
    {
        short8 fdu = *reinterpret_cast<const short8*>(base + (size_t)v * 1024 + 512 + l * 8);
#pragma unroll
        for (int j = 0; j < 8; ++j) fd[j] = bf2f((unsigned short)fdu[j]);
    }
    float acc[8] = {};
    float dn = 0.f;
    int s0 = rowstart[v], s1 = rowstart[v + 1];

    auto LD = [&](int i) -> short8 {
        return *reinterpret_cast<const short8*>(base + (size_t)csrc[i] * 1024 + l * 8);
    };
    auto ACC = [&](short8 su) {
        float sf[8];
        float p = 0.f;
#pragma unroll
        for (int j = 0; j < 8; ++j) {
            sf[j] = bf2f((unsigned short)su[j]);
            float e = sf[j] + fd[j];
            e = fmaxf(e, 0.2f * e);
            p += e * at[j];
        }
        p += __shfl_xor(p, 1, 4);
        p += __shfl_xor(p, 2, 4);
        float ex = __expf(p);
#pragma unroll
        for (int j = 0; j < 8; ++j) acc[j] += ex * sf[j];
        dn += ex;
    };
    const short8 z8 = {0, 0, 0, 0, 0, 0, 0, 0};
    short8 c0 = z8, c1 = z8, c2 = z8, c3 = z8;
    int i = s0;
    if (i     < s1) c0 = LD(i);
    if (i + 1 < s1) c1 = LD(i + 1);
    if (i + 2 < s1) c2 = LD(i + 2);
    if (i + 3 < s1) c3 = LD(i + 3);
    for (; i + 4 < s1; i += 4) {
        short8 n0 = LD(i + 4);
        short8 n1 = (i + 5 < s1) ? LD(i + 5) : z8;
        short8 n2 = (i + 6 < s1) ? LD(i + 6) : z8;
        short8 n3 = (i + 7 < s1) ? LD(i + 7) : z8;
        ACC(c0); ACC(c1); ACC(c2); ACC(c3);
        c0 = n0; c1 = n1; c2 = n2; c3 = n3;
    }
    if (i     < s1) ACC(c0);
    if (i + 1 < s1) ACC(c1);
    if (i + 2 < s1) ACC(c2);
    if (i + 3 < s1) ACC(c3);

    float* np = num + (size_t)v * 512 + l * 8;
    *reinterpret_cast<float4*>(np)     = make_float4(acc[0], acc[1], acc[2], acc[3]);
    *reinterpret_cast<float4*>(np + 4) = make_float4(acc[4], acc[5], acc[6], acc[7]);
    if ((l & 3) == 0) den[(size_t)v * 16 + (l >> 2)] = dn;
}

// ---------------- final classifier
__global__ void final_lin(const float* __restrict__ h1, const float* __restrict__ newF,
                          const float* __restrict__ h3, const float* __restrict__ W,
                          const float* __restrict__ bias, float* __restrict__ out, int n)
{
    int gid = blockIdx.x * blockDim.x + threadIdx.x;
    if (gid >= n * 6) return;
    int v = gid / 6, o = gid - v * 6;
    float s = bias[o];
    const float* a = h1 + (size_t)v * 64;
#pragma unroll 8
    for (int r = 0; r < 64; ++r) s += a[r] * W[r * 6 + o];
    const float* b = newF + (size_t)v * 8;
#pragma unroll
    for (int r = 0; r < 8; ++r) s += b[r] * W[(64 + r) * 6 + o];
    const float* c = h3 + (size_t)v * 64;
#pragma unroll 8
    for (int r = 0; r < 64; ++r) s += c[r] * W[(72 + r) * 6 + o];
    out[gid] = s;
}

// ----------------------------------------------------------------------------
extern "C" void kernel_launch(void* const* d_in, const int* in_sizes, int n_in,
                              void* d_out, int out_size, void* d_ws, size_t ws_size,
                              hipStream_t stream)
{
    const float* text   = (const float*)d_in[0];
    const float* audio  = (const float*)d_in[1];
    const float* vision = (const float*)d_in[2];
    const int*   esrc   = (const int*)d_in[3];
    const int*   edst   = (const int*)d_in[4];
    const float* W_audio = (const float*)d_in[5];  const float* b_audio = (const float*)d_in[6];
    const float* W_vision= (const float*)d_in[7];  const float* b_vision= (const float*)d_in[8];
    const float* W_text  = (const float*)d_in[9];  const float* b_text  = (const float*)d_in[10];
    const float* Wih_f = (const float*)d_in[11]; const float* Whh_f = (const float*)d_in[12];
    const float* bih_f = (const float*)d_in[13]; const float* bhh_f = (const float*)d_in[14];
    const float* Wih_b = (const float*)d_in[15]; const float* Whh_b = (const float*)d_in[16];
    const float* bih_b = (const float*)d_in[17]; const float* bhh_b = (const float*)d_in[18];
    const float* W_gc  = (const float*)d_in[19]; const float* b_gc  = (const float*)d_in[20];
    const float* Wsrc2 = (const float*)d_in[21]; const float* bsrc2 = (const float*)d_in[22];
    const float* Wdst2 = (const float*)d_in[23]; const float* bdst2 = (const float*)d_in[24];
    const float* attn2 = (const float*)d_in[25]; const float* Wres2 = (const float*)d_in[26];
    const float* Wsrc0 = (const float*)d_in[27]; const float* bsrc0 = (const float*)d_in[28];
    const float* Wdst0 = (const float*)d_in[29]; const float* bdst0 = (const float*)d_in[30];
    const float* attn0 = (const float*)d_in[31]; const float* Wres0 = (const float*)d_in[32];
    const float* Wsrc1 = (const float*)d_in[33]; const float* bsrc1 = (const float*)d_in[34];
    const float* Wdst1 = (const float*)d_in[35]; const float* bdst1 = (const float*)d_in[36];
    const float* attn1 = (const float*)d_in[37]; const float* Wres1 = (const float*)d_in[38];
    const float* W_lin = (const float*)d_in[39]; const float* b_lin = (const float*)d_in[40];
    float* out = (float*)d_out;

    const int n = in_sizes[0] / 1024;   // 12000
    const int E = in_sizes[3];          // 192000
    const int B = n / 120;              // 100

    // ---- workspace carve (256B aligned)
    char* p = (char*)d_ws;
    auto alloc_f = [&](size_t cnt) { float* r = (float*)p; p += ((cnt * 4 + 255) / 256) * 256; return r; };
    auto alloc_h = [&](size_t cnt) { unsigned short* r = (unsigned short*)p; p += ((cnt * 2 + 255) / 256) * 256; return r; };
    auto alloc_i = [&](size_t cnt) { int* r = (int*)p; p += ((cnt * 4 + 255) / 256) * 256; return r; };
    float*          stackFT = alloc_f((size_t)n * 192);
    unsigned short* stackBF = alloc_h((size_t)n * 192);
    unsigned short* hbufBF  = alloc_h((size_t)n * 192);
    unsigned short* encW    = alloc_h(163840);
    float* xWf     = alloc_f((size_t)n * 16);
    float* xWb     = alloc_f((size_t)n * 16);
    float* newF    = alloc_f((size_t)n * 8);
    float* big0    = alloc_f((size_t)n * 512);
    float* big1    = alloc_f((size_t)n * 512);
    float* big2    = alloc_f((size_t)n * 512);
    float* den     = alloc_f((size_t)n * 16);
    float* h3      = alloc_f((size_t)n * 64);
    float* h1s     = alloc_f((size_t)n * 64);   // hosts packed weights until gat1 edge writes it
    float* rs_out  = alloc_f(n);
    float* rs_in   = alloc_f(n);
    int* zero_base = alloc_i((size_t)3 * n);
    int* degout = zero_base;
    int* degin  = zero_base + n;
    int* cursor = zero_base + 2 * n;
    int* rowstart = alloc_i((size_t)n + 1);
    int* perm     = alloc_i((size_t)E);
    if ((size_t)(p - (char*)d_ws) > ws_size) return;

    // packed weights live in h1s (dead until gat1 edge): 479232 shorts + 1440 floats
    unsigned short* Wall = (unsigned short*)h1s;
    float* ball = h1s + 240000;
    const unsigned short* Wp_gc   = Wall;
    const unsigned short* Wp_g2   = Wall + 36864;
    const unsigned short* Wp_g0   = Wall + 73728;
    const unsigned short* Wp_r0   = Wall + 270336;
    const unsigned short* Wp_g1   = Wall + 368640;
    const unsigned short* Wp_lstm = Wall + 466944;
    const float* bp_g2   = ball;
    const float* bp_g0   = ball + 192;
    const float* bp_g1   = ball + 1216;
    const float* bp_lstm = ball + 1408;

    // ---- graph preprocessing + one fused weight-pack
    hipMemsetAsync(zero_base, 0, (size_t)3 * n * 4, stream);
    pack_all<<<(480672 + 255) / 256, 256, 0, stream>>>(
        W_text, W_audio, W_vision, W_gc,
        Wsrc2, Wdst2, Wres2, bsrc2, bdst2,
        Wsrc0, Wdst0, bsrc0, bdst0, Wres0,
        Wsrc1, Wdst1, Wres1, bsrc1, bdst1,
        Wih_f, Wih_b, bih_f, bhh_f, bih_b, bhh_b,
        (_Float16*)encW, Wall, ball);
    deg_kernel<<<(E + 255) / 256, 256, 0, stream>>>(esrc, edst, degout, degin, E);
    scan_kernel<<<1, 1024, 0, stream>>>(degin, degout, rowstart, rs_out, rs_in, n);
    perm_kernel<<<(E + 255) / 256, 256, 0, stream>>>(edst, rowstart, cursor, perm, E);
    gather_src_kernel<<<(E + 255) / 256, 256, 0, stream>>>(esrc, perm, E);
    const int* csrc = perm;

    auto gemm = [&](auto mf_tag, auto om_tag, const unsigned short* A, const unsigned short* Bm,
                    const float* bias, const float* rsc, void* Cp,
                    const float* fnum, const float* fden, int M, int Nb, int K, int ldc) {
        constexpr int MF = decltype(mf_tag)::value;
        constexpr int OM = decltype(om_tag)::value;
        dim3 grid((M + 64 * MF - 1) / (64 * MF), Nb / 64);
        gemm_v7<MF, OM><<<grid, 256, 0, stream>>>(A, Bm, bias, rsc, Cp, fnum, fden, M, Nb, K, ldc);
    };
    using I1 = std::integral_constant<int, 1>;
    using I2 = std::integral_constant<int, 2>;
    using O1 = std::integral_constant<int, 1>;
    using O2 = std::integral_constant<int, 2>;
    using O3 = std::integral_constant<int, 3>;

    // ---- modality encoders (barrier-free f16 MFMA, LDS-transposed epilogue)
    {
        int waves = 3 * (n >> 4);
        enc_f16v6<<<(waves * 64 + 255) / 256, 256, 0, stream>>>(
            text, audio, vision, (const _Float16*)encW,
            b_text, b_audio, b_vision, stackFT, stackBF, n);
    }

    // ---- BiLSTM: xW via MFMA GEMM (transposed scatter epilogue), then sequential scan
    gemm(I1{}, O3{}, stackBF, Wp_lstm, bp_lstm, nullptr, xWf, xWb, nullptr, n, 64, 192, 64);
    lstm_seq2<<<(2 * B + 3) / 4, 64, 0, stream>>>(xWf, xWb, Whh_f, Whh_b, newF, B);

    // ---- GraphConv imputation + L1 norm -> hbufBF (bf16)
    gemm(I1{}, O1{}, stackBF, Wp_gc, nullptr, rs_out, big0, nullptr, nullptr, n, 192, 192, 192);
    gc_combine5<<<(n + 3) / 4, 256, 0, stream>>>(stackFT, (const unsigned short*)big0,
                                                 rowstart, csrc, rs_in, b_gc, hbufBF, n);

    // ---- gat2: packed src|dst|res GEMM -> big0 bf16 [n,192], fused edge -> h3
    gemm(I1{}, O1{}, hbufBF, Wp_g2, bp_g2, nullptr, big0, nullptr, nullptr, n, 192, 192, 192);
    gat_edge4c<<<(n + 15) / 16, 256, 0, stream>>>((const unsigned short*)big0, attn2, rowstart, csrc, h3, n);

    // ---- gat0: packed src|dst GEMM -> big0 bf16 [n,1024]; edge -> big2/den;
    //            res GEMM with fused finalize -> big1 bf16 [n,512]
    gemm(I2{}, O1{}, hbufBF, Wp_g0, bp_g0, nullptr, big0, nullptr, nullptr, n, 1024, 192, 1024);
    gat_edge32b<<<(n + 3) / 4, 256, 0, stream>>>((const unsigned short*)big0, attn0, rowstart, csrc, big2, den, n);
    gemm(I1{}, O2{}, hbufBF, Wp_r0, nullptr, nullptr, big1, big2, den, n, 512, 192, 512);

    // ---- gat1: packed src|dst|res GEMM (A = big1 bf16 [n,512]) -> big0 bf16 [n,192], fused edge -> h1s
    gemm(I1{}, O1{}, (const unsigned short*)big1, Wp_g1, bp_g1, nullptr, big0, nullptr, nullptr, n, 192, 512, 192);
    gat_edge4c<<<(n + 15) / 16, 256, 0, stream>>>((const unsigned short*)big0, attn1, rowstart, csrc, h1s, n);

    // ---- final classifier
    final_lin<<<(n * 6 + 255) / 256, 256, 0, stream>>>(h1s, newF, h3, W_lin, b_lin, out, n);
}

// Round 15
// 326.990 us; speedup vs baseline: 1.0964x; 1.0136x over previous
//
#include <hip/hip_runtime.h>

typedef __attribute__((ext_vector_type(8))) short short8;
typedef __attribute__((ext_vector_type(4))) float f32x4;
typedef _Float16 half8v __attribute__((ext_vector_type(8)));

__device__ __forceinline__ unsigned short f2bf(float f) {
    unsigned u = __float_as_uint(f);
    u += 0x7FFFu + ((u >> 16) & 1u);
    return (unsigned short)(u >> 16);
}
__device__ __forceinline__ float bf2f(unsigned short h) {
    return __uint_as_float((unsigned)h << 16);
}

// =====================================================================
// gemm_v7: C[M,Nb] = A[M,K](bf16) @ B[K,Nb](bf16, pre-packed) (+bias)(*rowscale)
// OUTMODE: 0=f32, 1=bf16, 2=bf16+fused GAT finalize, 3=LSTM transposed scatter
template<int MF, int OUTMODE>
__global__ __launch_bounds__(256)
void gemm_v7(const unsigned short* __restrict__ A, const unsigned short* __restrict__ B,
             const float* __restrict__ bias, const float* __restrict__ rowscale,
             void* __restrict__ Cv, const float* __restrict__ fin_num,
             const float* __restrict__ fin_den,
             int M, int Nb, int K, int ldc)
{
    __shared__ alignas(16) unsigned short As[MF * 64 * 32];
    __shared__ alignas(16) unsigned short Bs[4 * 64 * 8];
    const int t = threadIdx.x;
    const int w = t >> 6, l = t & 63;
    const int r16 = l & 15, kg = l >> 4;
    const int row0 = blockIdx.x * (64 * MF);
    const int col0 = blockIdx.y * 64;
    const int bcol = t & 63, bkg = t >> 6;

    f32x4 acc[MF][4] = {};
    const short8 z8 = {0, 0, 0, 0, 0, 0, 0, 0};

    int srow[MF], sch[MF];
    bool va[MF];
    const unsigned short* aptr[MF];
#pragma unroll
    for (int it = 0; it < MF; ++it) {
        int idx = it * 256 + t;
        srow[it] = idx >> 2; sch[it] = idx & 3;
        int gm = row0 + srow[it];
        va[it] = gm < M;
        aptr[it] = A + (size_t)gm * K + sch[it] * 8;
    }
    const unsigned short* bptr = B + (size_t)(bkg * 8) * Nb + col0 + bcol;

    short8 pa[MF];
    unsigned short pbv[8];
#pragma unroll
    for (int it = 0; it < MF; ++it)
        pa[it] = va[it] ? *reinterpret_cast<const short8*>(aptr[it]) : z8;
#pragma unroll
    for (int j = 0; j < 8; ++j) pbv[j] = bptr[(size_t)j * Nb];

    for (int k0 = 0; k0 < K; k0 += 32) {
#pragma unroll
        for (int it = 0; it < MF; ++it)
            *reinterpret_cast<short8*>(&As[srow[it] * 32 + sch[it] * 8]) = pa[it];
        {
            short8 hv;
#pragma unroll
            for (int j = 0; j < 8; ++j) hv[j] = (short)pbv[j];
            *reinterpret_cast<short8*>(&Bs[bkg * 512 + bcol * 8]) = hv;
        }
        __syncthreads();
        if (k0 + 32 < K) {
#pragma unroll
            for (int it = 0; it < MF; ++it)
                pa[it] = va[it] ? *reinterpret_cast<const short8*>(aptr[it] + k0 + 32) : z8;
#pragma unroll
            for (int j = 0; j < 8; ++j) pbv[j] = bptr[(size_t)(k0 + 32 + j) * Nb];
        }
        short8 af[MF];
#pragma unroll
        for (int mi = 0; mi < MF; ++mi)
            af[mi] = *reinterpret_cast<const short8*>(&As[((w * MF + mi) * 16 + r16) * 32 + kg * 8]);
#pragma unroll
        for (int ni = 0; ni < 4; ++ni) {
            short8 bf = *reinterpret_cast<const short8*>(&Bs[kg * 512 + (ni * 16 + r16) * 8]);
#pragma unroll
            for (int mi = 0; mi < MF; ++mi)
                acc[mi][ni] = __builtin_amdgcn_mfma_f32_16x16x32_bf16(af[mi], bf, acc[mi][ni], 0, 0, 0);
        }
        __syncthreads();
    }
#pragma unroll
    for (int mi = 0; mi < MF; ++mi)
#pragma unroll
        for (int ni = 0; ni < 4; ++ni) {
            int col = col0 + ni * 16 + r16;
            float bv = bias ? bias[col] : 0.f;
#pragma unroll
            for (int r = 0; r < 4; ++r) {
                int gm = row0 + (w * MF + mi) * 16 + kg * 4 + r;
                if (gm < M) {
                    float val = acc[mi][ni][r] + bv;
                    if (rowscale) val *= rowscale[gm];
                    size_t idx = (size_t)gm * ldc + col;
                    if (OUTMODE == 0) {
                        ((float*)Cv)[idx] = val;
                    } else if (OUTMODE == 1) {
                        ((unsigned short*)Cv)[idx] = f2bf(val);
                    } else if (OUTMODE == 2) {
                        float d = fin_den[(size_t)gm * 16 + (col >> 5)];
                        float inv = (d > 0.f) ? __fdividef(1.f, d) : 0.f;
                        float o = fmaxf(fin_num[idx] * inv + val, 0.f);
                        ((unsigned short*)Cv)[idx] = f2bf(o);
                    } else {   // OUTMODE 3: LSTM transposed scatter
                        if (col < 32) {
                            int d = col >> 4, j = col & 15;
                            int bb = gm / 120, tt = gm - bb * 120;
                            float* dst = d ? (float*)fin_num : (float*)Cv;
                            dst[((size_t)bb * 16 + j) * 120 + tt] = val;
                        }
                    }
                }
            }
        }
}

// =====================================================================
// encoder v7: SPLIT-K cooperative block. One 16-row tile per BLOCK (2250
// blocks ≈ 8.8/CU); 4 waves each compute K/4; LDS partial reduce (one
// barrier); wave 0 does the transposed epilogue. Frag-packed weights.
__global__ __launch_bounds__(256)
void enc_f16v7(const float* __restrict__ text, const float* __restrict__ audio, const float* __restrict__ vision,
               const _Float16* __restrict__ Wf16,
               const float* __restrict__ bt, const float* __restrict__ ba, const float* __restrict__ bv,
               float* __restrict__ Cf, unsigned short* __restrict__ Cb, int M)
{
    __shared__ float part[3][16][65];
    __shared__ float tbuf[16][68];
    const int tpm = M >> 4;
    const int t3 = blockIdx.x;
    const int z = t3 / tpm;
    const int tidx = t3 - z * tpm;
    const int w = threadIdx.x >> 6, l = threadIdx.x & 63;
    const float* A  = (z == 0) ? text : (z == 1) ? audio : vision;
    const _Float16* Wbase = Wf16 + ((z == 0) ? 0 : (z == 1) ? 65536 : 98304);
    const float* bb = (z == 0) ? bt : (z == 1) ? ba : bv;
    const int KC = (z == 1) ? 16 : 32;
    const int KC4 = KC >> 2;

    const float* ap = A + (size_t)(tidx * 16 + (l & 15)) * (KC * 32) + (l >> 4) * 8 + (size_t)(w * KC4) * 32;
    const _Float16* Wp = Wbase + l * 8 + (size_t)(w * KC4) * 2048;

    f32x4 acc0 = {}, acc1 = {}, acc2 = {}, acc3 = {};
    float4 na0 = *reinterpret_cast<const float4*>(ap);
    float4 na1 = *reinterpret_cast<const float4*>(ap + 4);
    half8v nb0 = *reinterpret_cast<const half8v*>(Wp);
    half8v nb1 = *reinterpret_cast<const half8v*>(Wp + 512);
    half8v nb2 = *reinterpret_cast<const half8v*>(Wp + 1024);
    half8v nb3 = *reinterpret_cast<const half8v*>(Wp + 1536);

    for (int kc = 0; kc < KC4; ++kc) {
        float4 ca0 = na0, ca1 = na1;
        half8v cb0 = nb0, cb1 = nb1, cb2 = nb2, cb3 = nb3;
        if (kc + 1 < KC4) {
            const float* apn = ap + (kc + 1) * 32;
            na0 = *reinterpret_cast<const float4*>(apn);
            na1 = *reinterpret_cast<const float4*>(apn + 4);
            const _Float16* wpn = Wp + (size_t)(kc + 1) * 2048;
            nb0 = *reinterpret_cast<const half8v*>(wpn);
            nb1 = *reinterpret_cast<const half8v*>(wpn + 512);
            nb2 = *reinterpret_cast<const half8v*>(wpn + 1024);
            nb3 = *reinterpret_cast<const half8v*>(wpn + 1536);
        }
        half8v af;
        af[0] = (_Float16)ca0.x; af[1] = (_Float16)ca0.y;
        af[2] = (_Float16)ca0.z; af[3] = (_Float16)ca0.w;
        af[4] = (_Float16)ca1.x; af[5] = (_Float16)ca1.y;
        af[6] = (_Float16)ca1.z; af[7] = (_Float16)ca1.w;
        acc0 = __builtin_amdgcn_mfma_f32_16x16x32_f16(af, cb0, acc0, 0, 0, 0);
        acc1 = __builtin_amdgcn_mfma_f32_16x16x32_f16(af, cb1, acc1, 0, 0, 0);
        acc2 = __builtin_amdgcn_mfma_f32_16x16x32_f16(af, cb2, acc2, 0, 0, 0);
        acc3 = __builtin_amdgcn_mfma_f32_16x16x32_f16(af, cb3, acc3, 0, 0, 0);
    }

    if (w > 0) {
        float* pp = &part[w - 1][0][0];
#pragma unroll
        for (int j = 0; j < 4; ++j) {
            pp[(j)      * 65 + l] = acc0[j];
            pp[(4 + j)  * 65 + l] = acc1[j];
            pp[(8 + j)  * 65 + l] = acc2[j];
            pp[(12 + j) * 65 + l] = acc3[j];
        }
    }
    __syncthreads();
    if (w == 0) {
#pragma unroll
        for (int p = 0; p < 3; ++p) {
            const float* pp = &part[p][0][0];
#pragma unroll
            for (int j = 0; j < 4; ++j) {
                acc0[j] += pp[(j)      * 65 + l];
                acc1[j] += pp[(4 + j)  * 65 + l];
                acc2[j] += pp[(8 + j)  * 65 + l];
                acc3[j] += pp[(12 + j) * 65 + l];
            }
        }
        const int r16 = l & 15, hi = l >> 4;
#pragma unroll
        for (int cg = 0; cg < 4; ++cg) {
            f32x4 a = (cg == 0) ? acc0 : (cg == 1) ? acc1 : (cg == 2) ? acc2 : acc3;
            int col = cg * 16 + r16;
            float bvv = bb[col];
#pragma unroll
            for (int r = 0; r < 4; ++r)
                tbuf[hi * 4 + r][col] = a[r] + bvv;
        }
#pragma unroll
        for (int r = 0; r < 16; ++r) {
            float val = tbuf[r][l];
            size_t idx = (size_t)(tidx * 16 + r) * 192 + z * 64 + l;
            Cf[idx] = val;
            Cb[idx] = f2bf(val);
        }
    }
}

// =====================================================================
// one fused weight-pack kernel (also: LSTM weights/biases + edge degree counts)
__global__ void pack_all(const float* __restrict__ Wt, const float* __restrict__ Wa, const float* __restrict__ Wv,
                         const float* __restrict__ Wgc,
                         const float* __restrict__ Ws2, const float* __restrict__ Wd2, const float* __restrict__ Wr2,
                         const float* __restrict__ bs2, const float* __restrict__ bd2,
                         const float* __restrict__ Ws0, const float* __restrict__ Wd0,
                         const float* __restrict__ bs0, const float* __restrict__ bd0,
                         const float* __restrict__ Wr0,
                         const float* __restrict__ Ws1, const float* __restrict__ Wd1, const float* __restrict__ Wr1,
                         const float* __restrict__ bs1, const float* __restrict__ bd1,
                         const float* __restrict__ Wihf, const float* __restrict__ Wihb,
                         const float* __restrict__ bihf, const float* __restrict__ bhhf,
                         const float* __restrict__ bihb, const float* __restrict__ bhhb,
                         const int* __restrict__ esrc, const int* __restrict__ edst,
                         int* degout, int* degin, int E,
                         _Float16* __restrict__ encW, unsigned short* __restrict__ Wall, float* __restrict__ ball)
{
    int gid = blockIdx.x * blockDim.x + threadIdx.x;
    if (gid < E) {
        atomicAdd(&degout[esrc[gid]], 1);
        atomicAdd(&degin[edst[gid]], 1);
    }
    if (gid < 163840) {
        const float* Wsrcp;
        int base;
        if (gid < 65536)      { base = 0;     Wsrcp = Wt; }
        else if (gid < 98304) { base = 65536; Wsrcp = Wa; }
        else                  { base = 98304; Wsrcp = Wv; }
        int i = gid - base;
        int kc = i >> 11, r = i & 2047;
        int cg = r >> 9, lane = (r >> 3) & 63, j = r & 7;
        int k = kc * 32 + (lane >> 4) * 8 + j;
        int col = cg * 16 + (lane & 15);
        encW[gid] = (_Float16)Wsrcp[k * 64 + col];
    }
    if (gid < 36864) {
        Wall[gid] = f2bf(Wgc[gid]);
    } else if (gid < 73728) {
        int i = gid - 36864, k = i / 192, c = i - k * 192;
        float v = (c < 64) ? Ws2[k * 64 + c] : (c < 128) ? Wd2[k * 64 + c - 64] : Wr2[k * 64 + c - 128];
        Wall[gid] = f2bf(v);
    } else if (gid < 270336) {
        int i = gid - 73728, k = i >> 10, c = i & 1023;
        float v = (c < 512) ? Ws0[k * 512 + c] : Wd0[k * 512 + c - 512];
        Wall[gid] = f2bf(v);
    } else if (gid < 368640) {
        Wall[gid] = f2bf(Wr0[gid - 270336]);
    } else if (gid < 466944) {
        int i = gid - 368640, k = i / 192, c = i - k * 192;
        float v = (c < 64) ? Ws1[k * 64 + c] : (c < 128) ? Wd1[k * 64 + c - 64] : Wr1[k * 64 + c - 128];
        Wall[gid] = f2bf(v);
    } else if (gid < 479232) {
        int i = gid - 466944, k = i >> 6, c = i & 63;
        float v = (c < 16) ? Wihf[c * 192 + k] : (c < 32) ? Wihb[(c - 16) * 192 + k] : 0.f;
        Wall[gid] = f2bf(v);
    } else if (gid < 480672) {
        int i = gid - 479232;
        float v;
        if (i < 192)       v = (i < 64) ? bs2[i] : (i < 128) ? bd2[i - 64] : 0.f;
        else if (i < 1216) { int j = i - 192; v = (j < 512) ? bs0[j] : bd0[j - 512]; }
        else if (i < 1408) { int j = i - 1216; v = (j < 64) ? bs1[j] : (j < 128) ? bd1[j - 64] : 0.f; }
        else               { int j = i - 1408; v = (j < 16) ? (bihf[j] + bhhf[j]) : (bihb[j - 16] + bhhb[j - 16]); }
        ball[i] = v;
    }
}

// ---------------- graph preprocessing
__global__ __launch_bounds__(1024)
void scan_kernel(const int* __restrict__ degin, const int* __restrict__ degout,
                 int* __restrict__ rowstart, float* __restrict__ rso, float* __restrict__ rsi, int n)
{
    __shared__ int part[1024];
    int t = threadIdx.x;
    int chunk = (n + 1023) / 1024;
    int s = 0;
    for (int i = 0; i < chunk; ++i) {
        int idx = t * chunk + i;
        if (idx < n) s += degin[idx];
    }
    part[t] = s;
    __syncthreads();
    for (int o = 1; o < 1024; o <<= 1) {
        int v = (t >= o) ? part[t - o] : 0;
        __syncthreads();
        part[t] += v;
        __syncthreads();
    }
    int run = (t > 0) ? part[t - 1] : 0;
    for (int i = 0; i < chunk; ++i) {
        int idx = t * chunk + i;
        if (idx < n) {
            rowstart[idx] = run; run += degin[idx];
            rso[idx] = rsqrtf((float)max(degout[idx], 1));
            rsi[idx] = rsqrtf((float)max(degin[idx], 1));
        }
    }
    if (t == 1023) rowstart[n] = part[1023];
}

__global__ void perm_kernel(const int* __restrict__ dst, const int* __restrict__ rowstart,
                            int* cursor, int* __restrict__ perm, int E)
{
    int e = blockIdx.x * blockDim.x + threadIdx.x;
    if (e < E) {
        int v = dst[e];
        int p = atomicAdd(&cursor[v], 1);
        perm[rowstart[v] + p] = e;
    }
}

__global__ void gather_src_kernel(const int* __restrict__ esrc, int* perm, int E)
{
    int i = blockIdx.x * blockDim.x + threadIdx.x;
    if (i < E) perm[i] = esrc[perm[i]];
}

// ---------------- LSTM sequential scan
__device__ __forceinline__ float fsigm(float x) { return __fdividef(1.f, 1.f + __expf(-x)); }
__device__ __forceinline__ float ftanh(float x) { return 1.f - __fdividef(2.f, __expf(2.f * x) + 1.f); }

template<int DIR>
__device__ void lstm_chain(const float* __restrict__ xw, const float* __restrict__ whh,
                           float* __restrict__ newF, int b)
{
    int j = threadIdx.x & 15;
    int k = j & 3;
    float4 w = *reinterpret_cast<const float4*>(whh + j * 4);
    const float* xp = xw + ((size_t)b * 16 + j) * 120;
    float h0 = 0.f, h1 = 0.f, h2 = 0.f, h3 = 0.f, cst = 0.f;
    int tb0 = DIR ? 108 : 0;
    float4 a0 = *reinterpret_cast<const float4*>(xp + tb0);
    float4 a1 = *reinterpret_cast<const float4*>(xp + tb0 + 4);
    float4 a2 = *reinterpret_cast<const float4*>(xp + tb0 + 8);
    for (int ch = 0; ch < 10; ++ch) {
        float4 b0 = a0, b1 = a1, b2 = a2;
        if (ch < 9) {
            int nt = DIR ? (96 - ch * 12) : (12 + ch * 12);
            b0 = *reinterpret_cast<const float4*>(xp + nt);
            b1 = *reinterpret_cast<const float4*>(xp + nt + 4);
            b2 = *reinterpret_cast<const float4*>(xp + nt + 8);
        }
        float zz[12] = {a0.x, a0.y, a0.z, a0.w, a1.x, a1.y, a1.z, a1.w, a2.x, a2.y, a2.z, a2.w};
        int tbase = DIR ? (108 - ch * 12) : (ch * 12);
#pragma unroll
        for (int ii = 0; ii < 12; ++ii) {
            int idx = DIR ? (11 - ii) : ii;
            float z = zz[idx] + ((w.x * h0 + w.y * h1) + (w.z * h2 + w.w * h3));
            float zi = __shfl(z, k, 16);
            float zf = __shfl(z, k + 4, 16);
            float zg = __shfl(z, k + 8, 16);
            float zo = __shfl(z, k + 12, 16);
            float ig = fsigm(zi), fg = fsigm(zf), gg = ftanh(zg), og = fsigm(zo);
            cst = fg * cst + ig * gg;
            float hn = og * ftanh(cst);
            h0 = __shfl(hn, 0, 16); h1 = __shfl(hn, 1, 16);
            h2 = __shfl(hn, 2, 16); h3 = __shfl(hn, 3, 16);
            if (j < 4) newF[((size_t)b * 120 + tbase + idx) * 8 + DIR * 4 + j] = hn;
        }
        a0 = b0; a1 = b1; a2 = b2;
    }
}

__global__ __launch_bounds__(64)
void lstm_seq2(const float* __restrict__ xWf, const float* __restrict__ xWb,
               const float* __restrict__ Whhf, const float* __restrict__ Whhb,
               float* __restrict__ newF, int B)
{
    int sub = threadIdx.x >> 4;
    int chain = blockIdx.x * 4 + sub;
    if (chain >= 2 * B) return;
    int d = chain / B;
    int b = chain - d * B;
    if (d == 0) lstm_chain<0>(xWf, Whhf, newF, b);
    else        lstm_chain<1>(xWb, Whhb, newF, b);
}

// ---------------- GraphConv combine + L1 norm: 2-edge software pipeline
__global__ __launch_bounds__(256)
void gc_combine5(const float* __restrict__ stackFT, const unsigned short* __restrict__ hw,
                 const int* __restrict__ rowstart, const int* __restrict__ csrc,
                 const float* __restrict__ rs_in,
                 const float* __restrict__ b_gc, unsigned short* __restrict__ hB, int n)
{
    int v = blockIdx.x * 4 + (threadIdx.x >> 6);
    int l = threadIdx.x & 63;
    if (v >= n) return;
    int s0 = rowstart[v], s1 = rowstart[v + 1];
    float sum0 = 0.f, sum1 = 0.f, sum2 = 0.f;

    unsigned short a0 = 0, a1 = 0, a2 = 0, b0 = 0, b1 = 0, b2 = 0;
    auto LD = [&](int i, unsigned short& x0, unsigned short& x1, unsigned short& x2) {
        const unsigned short* hr = hw + (size_t)csrc[i] * 192 + l;
        x0 = hr[0]; x1 = hr[64]; x2 = hr[128];
    };
    int i = s0;
    if (i < s1) LD(i, a0, a1, a2);
    if (i + 1 < s1) LD(i + 1, b0, b1, b2);
    for (; i + 2 < s1; i += 2) {
        unsigned short n0, n1, n2, m0 = 0, m1 = 0, m2 = 0;
        LD(i + 2, n0, n1, n2);
        if (i + 3 < s1) LD(i + 3, m0, m1, m2);
        sum0 += bf2f(a0) + bf2f(b0);
        sum1 += bf2f(a1) + bf2f(b1);
        sum2 += bf2f(a2) + bf2f(b2);
        a0 = n0; a1 = n1; a2 = n2; b0 = m0; b1 = m1; b2 = m2;
    }
    if (i < s1) { sum0 += bf2f(a0); sum1 += bf2f(a1); sum2 += bf2f(a2); }
    if (i + 1 < s1) { sum0 += bf2f(b0); sum1 += bf2f(b1); sum2 += bf2f(b2); }

    float ri = rs_in[v];
    const float* sf = stackFT + (size_t)v * 192 + l;
    float v0 = 0.5f * (sf[0]   + sum0 * ri + b_gc[l]);
    float v1 = 0.5f * (sf[64]  + sum1 * ri + b_gc[l + 64]);
    float v2 = 0.5f * (sf[128] + sum2 * ri + b_gc[l + 128]);
    float r = fabsf(v0) + fabsf(v1) + fabsf(v2);
#pragma unroll
    for (int o = 32; o; o >>= 1) r += __shfl_xor(r, o);
    float inv = __fdividef(1.f, fmaxf(r, 1e-12f));
    unsigned short* hp = hB + (size_t)v * 192 + l;
    hp[0]   = f2bf(v0 * inv);
    hp[64]  = f2bf(v1 * inv);
    hp[128] = f2bf(v2 * inv);
}

// ---------------- GATv2 F=4 (HF=64): 16 lanes/node, 4-edge pipeline, fused epilogue
__global__ __launch_bounds__(256)
void gat_edge4c(const unsigned short* __restrict__ base,
                const float* __restrict__ attn,
                const int* __restrict__ rowstart, const int* __restrict__ csrc,
                float* __restrict__ outp, int n)
{
    int v = blockIdx.x * 16 + (threadIdx.x >> 4);
    int l = threadIdx.x & 15;
    if (v >= n) return;
    float4 at = *reinterpret_cast<const float4*>(attn + l * 4);
    ushort4 fdu = *reinterpret_cast<const ushort4*>(base + (size_t)v * 192 + 64 + l * 4);
    float fd0 = bf2f(fdu.x), fd1 = bf2f(fdu.y), fd2 = bf2f(fdu.z), fd3 = bf2f(fdu.w);
    float ac0 = 0.f, ac1 = 0.f, ac2 = 0.f, ac3 = 0.f, dn = 0.f;
    int s0 = rowstart[v], s1 = rowstart[v + 1];

    auto LD = [&](int i) -> ushort4 {
        return *reinterpret_cast<const ushort4*>(base + (size_t)csrc[i] * 192 + l * 4);
    };
    auto ACC = [&](ushort4 su) {
        float s0f = bf2f(su.x), s1f = bf2f(su.y), s2f = bf2f(su.z), s3f = bf2f(su.w);
        float e0 = s0f + fd0; e0 = fmaxf(e0, 0.2f * e0);
        float e1 = s1f + fd1; e1 = fmaxf(e1, 0.2f * e1);
        float e2 = s2f + fd2; e2 = fmaxf(e2, 0.2f * e2);
        float e3 = s3f + fd3; e3 = fmaxf(e3, 0.2f * e3);
        float p = e0 * at.x + e1 * at.y + e2 * at.z + e3 * at.w;
        float ex = __expf(p);
        ac0 += ex * s0f; ac1 += ex * s1f; ac2 += ex * s2f; ac3 += ex * s3f;
        dn += ex;
    };
    const ushort4 zu = make_ushort4(0, 0, 0, 0);
    ushort4 c0 = zu, c1 = zu, c2 = zu, c3 = zu;
    int i = s0;
    if (i     < s1) c0 = LD(i);
    if (i + 1 < s1) c1 = LD(i + 1);
    if (i + 2 < s1) c2 = LD(i + 2);
    if (i + 3 < s1) c3 = LD(i + 3);
    for (; i + 4 < s1; i += 4) {
        ushort4 n0 = LD(i + 4);
        ushort4 n1 = (i + 5 < s1) ? LD(i + 5) : zu;
        ushort4 n2 = (i + 6 < s1) ? LD(i + 6) : zu;
        ushort4 n3 = (i + 7 < s1) ? LD(i + 7) : zu;
        ACC(c0); ACC(c1); ACC(c2); ACC(c3);
        c0 = n0; c1 = n1; c2 = n2; c3 = n3;
    }
    if (i     < s1) ACC(c0);
    if (i + 1 < s1) ACC(c1);
    if (i + 2 < s1) ACC(c2);
    if (i + 3 < s1) ACC(c3);

    ushort4 ru = *reinterpret_cast<const ushort4*>(base + (size_t)v * 192 + 128 + l * 4);
    float inv = (dn > 0.f) ? __fdividef(1.f, dn) : 0.f;
    float4 o;
    o.x = fmaxf(ac0 * inv + bf2f(ru.x), 0.f);
    o.y = fmaxf(ac1 * inv + bf2f(ru.y), 0.f);
    o.z = fmaxf(ac2 * inv + bf2f(ru.z), 0.f);
    o.w = fmaxf(ac3 * inv + bf2f(ru.w), 0.f);
    *reinterpret_cast<float4*>(outp + (size_t)v * 64 + l * 4) = o;
}

// ---------------- GATv2 F=32 (HF=512): one wave per node, 8 elems/lane, 4-edge pipeline
__global__ __launch_bounds__(256)
void gat_edge32b(const unsigned short* __restrict__ base,
                 const float* __restrict__ attn,
                 const int* __restrict__ rowstart, const int* __restrict__ csrc,
                 float* __restrict__ num, float* __restrict__ den, int n)
{
    int v = blockIdx.x * 4 + (threadIdx.x >> 6);
    int l = threadIdx.x & 63;
    if (v >= n) return;
    float at[8];
    {
        float4 aA = *reinterpret_cast<const float4*>(attn + l * 8);
        float4 aB = *reinterpret_cast<const float4*>(attn + l * 8 + 4);
        at[0] = aA.x; at[1] = aA.y; at[2] = aA.z; at[3] = aA.w;
        at[4] = aB.x; at[5] = aB.y; at[6] = aB.z; at[7] = aB.w;
    }
    float fd[8];
    {
        short8 fdu = *reinterpret_cast<const short8*>(base + (size_t)v * 1024 + 512 + l * 8);
#pragma unroll
        for (int j = 0; j < 8; ++j) fd[j] = bf2f((unsigned short)fdu[j]);
    }
    float acc[8] = {};
    float dn = 0.f;
    int s0 = rowstart[v], s1 = rowstart[v + 1];

    auto LD = [&](int i) -> short8 {
        return *reinterpret_cast<const short8*>(base + (size_t)csrc[i] * 1024 + l * 8);
    };
    auto ACC = [&](short8 su) {
        float sf[8];
        float p = 0.f;
#pragma unroll
        for (int j = 0; j < 8; ++j) {
            sf[j] = bf2f((unsigned short)su[j]);
            float e = sf[j] + fd[j];
            e = fmaxf(e, 0.2f * e);
            p += e * at[j];
        }
        p += __shfl_xor(p, 1, 4);
        p += __shfl_xor(p, 2, 4);
        float ex = __expf(p);
#pragma unroll
        for (int j = 0; j < 8; ++j) acc[j] += ex * sf[j];
        dn += ex;
    };
    const short8 z8 = {0, 0, 0, 0, 0, 0, 0, 0};
    short8 c0 = z8, c1 = z8, c2 = z8, c3 = z8;
    int i = s0;
    if (i     < s1) c0 = LD(i);
    if (i + 1 < s1) c1 = LD(i + 1);
    if (i + 2 < s1) c2 = LD(i + 2);
    if (i + 3 < s1) c3 = LD(i + 3);
    for (; i + 4 < s1; i += 4) {
        short8 n0 = LD(i + 4);
        short8 n1 = (i + 5 < s1) ? LD(i + 5) : z8;
        short8 n2 = (i + 6 < s1) ? LD(i + 6) : z8;
        short8 n3 = (i + 7 < s1) ? LD(i + 7) : z8;
        ACC(c0); ACC(c1); ACC(c2); ACC(c3);
        c0 = n0; c1 = n1; c2 = n2; c3 = n3;
    }
    if (i     < s1) ACC(c0);
    if (i + 1 < s1) ACC(c1);
    if (i + 2 < s1) ACC(c2);
    if (i + 3 < s1) ACC(c3);

    float* np = num + (size_t)v * 512 + l * 8;
    *reinterpret_cast<float4*>(np)     = make_float4(acc[0], acc[1], acc[2], acc[3]);
    *reinterpret_cast<float4*>(np + 4) = make_float4(acc[4], acc[5], acc[6], acc[7]);
    if ((l & 3) == 0) den[(size_t)v * 16 + (l >> 2)] = dn;
}

// ---------------- final classifier
__global__ void final_lin(const float* __restrict__ h1, const float* __restrict__ newF,
                          const float* __restrict__ h3, const float* __restrict__ W,
                          const float* __restrict__ bias, float* __restrict__ out, int n)
{
    int gid = blockIdx.x * blockDim.x + threadIdx.x;
    if (gid >= n * 6) return;
    int v = gid / 6, o = gid - v * 6;
    float s = bias[o];
    const float* a = h1 + (size_t)v * 64;
#pragma unroll 8
    for (int r = 0; r < 64; ++r) s += a[r] * W[r * 6 + o];
    const float* b = newF + (size_t)v * 8;
#pragma unroll
    for (int r = 0; r < 8; ++r) s += b[r] * W[(64 + r) * 6 + o];
    const float* c = h3 + (size_t)v * 64;
#pragma unroll 8
    for (int r = 0; r < 64; ++r) s += c[r] * W[(72 + r) * 6 + o];
    out[gid] = s;
}

// ----------------------------------------------------------------------------
extern "C" void kernel_launch(void* const* d_in, const int* in_sizes, int n_in,
                              void* d_out, int out_size, void* d_ws, size_t ws_size,
                              hipStream_t stream)
{
    const float* text   = (const float*)d_in[0];
    const float* audio  = (const float*)d_in[1];
    const float* vision = (const float*)d_in[2];
    const int*   esrc   = (const int*)d_in[3];
    const int*   edst   = (const int*)d_in[4];
    const float* W_audio = (const float*)d_in[5];  const float* b_audio = (const float*)d_in[6];
    const float* W_vision= (const float*)d_in[7];  const float* b_vision= (const float*)d_in[8];
    const float* W_text  = (const float*)d_in[9];  const float* b_text  = (const float*)d_in[10];
    const float* Wih_f = (const float*)d_in[11]; const float* Whh_f = (const float*)d_in[12];
    const float* bih_f = (const float*)d_in[13]; const float* bhh_f = (const float*)d_in[14];
    const float* Wih_b = (const float*)d_in[15]; const float* Whh_b = (const float*)d_in[16];
    const float* bih_b = (const float*)d_in[17]; const float* bhh_b = (const float*)d_in[18];
    const float* W_gc  = (const float*)d_in[19]; const float* b_gc  = (const float*)d_in[20];
    const float* Wsrc2 = (const float*)d_in[21]; const float* bsrc2 = (const float*)d_in[22];
    const float* Wdst2 = (const float*)d_in[23]; const float* bdst2 = (const float*)d_in[24];
    const float* attn2 = (const float*)d_in[25]; const float* Wres2 = (const float*)d_in[26];
    const float* Wsrc0 = (const float*)d_in[27]; const float* bsrc0 = (const float*)d_in[28];
    const float* Wdst0 = (const float*)d_in[29]; const float* bdst0 = (const float*)d_in[30];
    const float* attn0 = (const float*)d_in[31]; const float* Wres0 = (const float*)d_in[32];
    const float* Wsrc1 = (const float*)d_in[33]; const float* bsrc1 = (const float*)d_in[34];
    const float* Wdst1 = (const float*)d_in[35]; const float* bdst1 = (const float*)d_in[36];
    const float* attn1 = (const float*)d_in[37]; const float* Wres1 = (const float*)d_in[38];
    const float* W_lin = (const float*)d_in[39]; const float* b_lin = (const float*)d_in[40];
    float* out = (float*)d_out;

    const int n = in_sizes[0] / 1024;   // 12000
    const int E = in_sizes[3];          // 192000
    const int B = n / 120;              // 100

    // ---- workspace carve (256B aligned)
    char* p = (char*)d_ws;
    auto alloc_f = [&](size_t cnt) { float* r = (float*)p; p += ((cnt * 4 + 255) / 256) * 256; return r; };
    auto alloc_h = [&](size_t cnt) { unsigned short* r = (unsigned short*)p; p += ((cnt * 2 + 255) / 256) * 256; return r; };
    auto alloc_i = [&](size_t cnt) { int* r = (int*)p; p += ((cnt * 4 + 255) / 256) * 256; return r; };
    float*          stackFT = alloc_f((size_t)n * 192);
    unsigned short* stackBF = alloc_h((size_t)n * 192);
    unsigned short* hbufBF  = alloc_h((size_t)n * 192);
    unsigned short* encW    = alloc_h(163840);
    float* xWf     = alloc_f((size_t)n * 16);
    float* xWb     = alloc_f((size_t)n * 16);
    float* newF    = alloc_f((size_t)n * 8);
    float* big0    = alloc_f((size_t)n * 512);
    float* big1    = alloc_f((size_t)n * 512);
    float* big2    = alloc_f((size_t)n * 512);
    float* den     = alloc_f((size_t)n * 16);
    float* h3      = alloc_f((size_t)n * 64);
    float* h1s     = alloc_f((size_t)n * 64);   // hosts packed weights until gat1 edge writes it
    float* rs_out  = alloc_f(n);
    float* rs_in   = alloc_f(n);
    int* zero_base = alloc_i((size_t)3 * n);
    int* degout = zero_base;
    int* degin  = zero_base + n;
    int* cursor = zero_base + 2 * n;
    int* rowstart = alloc_i((size_t)n + 1);
    int* perm     = alloc_i((size_t)E);
    if ((size_t)(p - (char*)d_ws) > ws_size) return;

    // packed weights live in h1s (dead until gat1 edge): 479232 shorts + 1440 floats
    unsigned short* Wall = (unsigned short*)h1s;
    float* ball = h1s + 240000;
    const unsigned short* Wp_gc   = Wall;
    const unsigned short* Wp_g2   = Wall + 36864;
    const unsigned short* Wp_g0   = Wall + 73728;
    const unsigned short* Wp_r0   = Wall + 270336;
    const unsigned short* Wp_g1   = Wall + 368640;
    const unsigned short* Wp_lstm = Wall + 466944;
    const float* bp_g2   = ball;
    const float* bp_g0   = ball + 192;
    const float* bp_g1   = ball + 1216;
    const float* bp_lstm = ball + 1408;

    // ---- graph preprocessing + one fused weight-pack (+degrees)
    hipMemsetAsync(zero_base, 0, (size_t)3 * n * 4, stream);
    pack_all<<<(480672 + 255) / 256, 256, 0, stream>>>(
        W_text, W_audio, W_vision, W_gc,
        Wsrc2, Wdst2, Wres2, bsrc2, bdst2,
        Wsrc0, Wdst0, bsrc0, bdst0, Wres0,
        Wsrc1, Wdst1, Wres1, bsrc1, bdst1,
        Wih_f, Wih_b, bih_f, bhh_f, bih_b, bhh_b,
        esrc, edst, degout, degin, E,
        (_Float16*)encW, Wall, ball);
    scan_kernel<<<1, 1024, 0, stream>>>(degin, degout, rowstart, rs_out, rs_in, n);
    perm_kernel<<<(E + 255) / 256, 256, 0, stream>>>(edst, rowstart, cursor, perm, E);
    gather_src_kernel<<<(E + 255) / 256, 256, 0, stream>>>(esrc, perm, E);
    const int* csrc = perm;

    auto gemm = [&](auto mf_tag, auto om_tag, const unsigned short* A, const unsigned short* Bm,
                    const float* bias, const float* rsc, void* Cp,
                    const float* fnum, const float* fden, int M, int Nb, int K, int ldc) {
        constexpr int MF = decltype(mf_tag)::value;
        constexpr int OM = decltype(om_tag)::value;
        dim3 grid((M + 64 * MF - 1) / (64 * MF), Nb / 64);
        gemm_v7<MF, OM><<<grid, 256, 0, stream>>>(A, Bm, bias, rsc, Cp, fnum, fden, M, Nb, K, ldc);
    };
    using I1 = std::integral_constant<int, 1>;
    using I2 = std::integral_constant<int, 2>;
    using O1 = std::integral_constant<int, 1>;
    using O2 = std::integral_constant<int, 2>;
    using O3 = std::integral_constant<int, 3>;

    // ---- modality encoders (split-K cooperative blocks, frag-packed weights)
    enc_f16v7<<<3 * (n >> 4), 256, 0, stream>>>(
        text, audio, vision, (const _Float16*)encW,
        b_text, b_audio, b_vision, stackFT, stackBF, n);

    // ---- BiLSTM: xW via MFMA GEMM (transposed scatter epilogue), then sequential scan
    gemm(I1{}, O3{}, stackBF, Wp_lstm, bp_lstm, nullptr, xWf, xWb, nullptr, n, 64, 192, 64);
    lstm_seq2<<<(2 * B + 3) / 4, 64, 0, stream>>>(xWf, xWb, Whh_f, Whh_b, newF, B);

    // ---- GraphConv imputation + L1 norm -> hbufBF (bf16)
    gemm(I1{}, O1{}, stackBF, Wp_gc, nullptr, rs_out, big0, nullptr, nullptr, n, 192, 192, 192);
    gc_combine5<<<(n + 3) / 4, 256, 0, stream>>>(stackFT, (const unsigned short*)big0,
                                                 rowstart, csrc, rs_in, b_gc, hbufBF, n);

    // ---- gat2: packed src|dst|res GEMM -> big0 bf16 [n,192], fused edge -> h3
    gemm(I1{}, O1{}, hbufBF, Wp_g2, bp_g2, nullptr, big0, nullptr, nullptr, n, 192, 192, 192);
    gat_edge4c<<<(n + 15) / 16, 256, 0, stream>>>((const unsigned short*)big0, attn2, rowstart, csrc, h3, n);

    // ---- gat0: packed src|dst GEMM -> big0 bf16 [n,1024]; edge -> big2/den;
    //            res GEMM with fused finalize -> big1 bf16 [n,512]
    gemm(I2{}, O1{}, hbufBF, Wp_g0, bp_g0, nullptr, big0, nullptr, nullptr, n, 1024, 192, 1024);
    gat_edge32b<<<(n + 3) / 4, 256, 0, stream>>>((const unsigned short*)big0, attn0, rowstart, csrc, big2, den, n);
    gemm(I1{}, O2{}, hbufBF, Wp_r0, nullptr, nullptr, big1, big2, den, n, 512, 192, 512);

    // ---- gat1: packed src|dst|res GEMM (A = big1 bf16 [n,512]) -> big0 bf16 [n,192], fused edge -> h1s
    gemm(I1{}, O1{}, (const unsigned short*)big1, Wp_g1, bp_g1, nullptr, big0, nullptr, nullptr, n, 192, 512, 192);
    gat_edge4c<<<(n + 15) / 16, 256, 0, stream>>>((const unsigned short*)big0, attn1, rowstart, csrc, h1s, n);

    // ---- final classifier
    final_lin<<<(n * 6 + 255) / 256, 256, 0, stream>>>(h1s, newF, h3, W_lin, b_lin, out, n);
}